// Round 7
// baseline (940.826 us; speedup 1.0000x reference)
//
#include <hip/hip_runtime.h>
#include <hip/hip_bf16.h>

// BiMamba: bidirectional Mamba2 forward, MI355X/gfx950.
// Per direction: in-proj (bf16 MFMA GEMM, A-row flip for backward) -> exact
// fp32 dt/log-decay (fused both-dir tiled GEMV) -> conv+silu for B/C once into
// per-chunk blobs -> chunked SSD scan (three 64^3 matmuls on MFMA) -> z GEMM
// -> gated RMSNorm -> combined out-proj+fusion GEMM into fp32 d_out.
// GEMM (round-7 = round-5 form, measured best): 128x128 tile, BK=32, async
// global->LDS (16B), DOUBLE-buffered LDS with ONE barrier per k-step. Round-6
// A/B showed counted-vmcnt 3-buf is null (structure is at its shape ceiling;
// the barrier drain was not the stall), so keep the simpler 2-buf form.
// NO block swizzle: natural x-major order gives xcd = blockIdx.x%8 -> per-XCD
// A working set (3.1 MB) is L2-resident (round-4 measured: swizzle broke it).
// Round-7: chunk_intra conv taps read DIRECTLY from global into registers at
// kernel top (T14 issue-early; L2-hot rows, latency hidden under B/C staging
// and the decay scan) -- the rawX LDS staging detour is deleted.
// Round-3: all scalar memory paths in the SSD chain vectorized to 16B (G13).

#define BATCHN 4
#define SEQL 4096
#define DMODEL 768
#define DINNER 1536
#define DSTATE 64
#define HN 24
#define CONVDIM 1664          // DINNER + 2*DSTATE
#define NROWS_XBC 3200        // DINNER + CONVDIM (in_w rows GEMMed; dt rows excluded)
#define NTOK (BATCHN*SEQL)    // 16384
#define NCHUNK 64             // SEQL / 64
#define LS 72                 // LDS stride (shorts) for chunk kernels
#define GBUF (128 * 32)       // one GEMM LDS buffer (shorts)

typedef short v8s __attribute__((ext_vector_type(8)));
typedef unsigned short v8u __attribute__((ext_vector_type(8)));
typedef float v4f __attribute__((ext_vector_type(4)));
typedef unsigned int v2u32 __attribute__((ext_vector_type(2)));
typedef __hip_bfloat16 bf16;

__device__ __forceinline__ int flip_row(int r) {
  return (r & ~4095) | (4095 - (r & 4095));
}
__device__ __forceinline__ float us2f(unsigned short u) {
  return __uint_as_float(((unsigned int)u) << 16);
}
__device__ __forceinline__ unsigned short f2us(float f) {
  bf16 b = __float2bfloat16(f);
  return __builtin_bit_cast(unsigned short, b);
}
// async 16B/lane global->LDS; LDS dest = wave-uniform base + lane*16
__device__ __forceinline__ void async16(const unsigned short* g, unsigned short* l) {
  __builtin_amdgcn_global_load_lds(
      (const __attribute__((address_space(1))) unsigned int*)(const void*)g,
      (__attribute__((address_space(3))) unsigned int*)(void*)l, 16, 0, 0);
}

// ---------------- cast kernels (4-wide) ----------------

__global__ void cast_x_kernel(const float* __restrict__ x, bf16* __restrict__ xf) {
  int idx = blockIdx.x * 256 + threadIdx.x;   // x4 elements
  v4f v = *(const v4f*)(x + (size_t)idx * 4);
  v2u32 o;
  o[0] = (unsigned int)f2us(v[0]) | ((unsigned int)f2us(v[1]) << 16);
  o[1] = (unsigned int)f2us(v[2]) | ((unsigned int)f2us(v[3]) << 16);
  *(v2u32*)((unsigned short*)xf + (size_t)idx * 4) = o;
}

__global__ void cast_kernel(const float* __restrict__ src, bf16* __restrict__ dst) {
  int idx = blockIdx.x * 256 + threadIdx.x;   // x4 elements
  v4f v = *(const v4f*)(src + (size_t)idx * 4);
  v2u32 o;
  o[0] = (unsigned int)f2us(v[0]) | ((unsigned int)f2us(v[1]) << 16);
  o[1] = (unsigned int)f2us(v[2]) | ((unsigned int)f2us(v[3]) << 16);
  *(v2u32*)((unsigned short*)dst + (size_t)idx * 4) = o;
}

// dst[j*cols+m] = src[j*src_stride+m]  (extract fus_w half), 4-wide (cols%4==0)
__global__ void cast_strided_kernel(const float* __restrict__ src, bf16* __restrict__ dst,
                                    int cols, int src_stride) {
  int idx4 = (blockIdx.x * 256 + threadIdx.x) * 4;
  int j = idx4 / cols, m = idx4 % cols;
  v4f v = *(const v4f*)(src + (size_t)j * src_stride + m);
  v2u32 o;
  o[0] = (unsigned int)f2us(v[0]) | ((unsigned int)f2us(v[1]) << 16);
  o[1] = (unsigned int)f2us(v[2]) | ((unsigned int)f2us(v[3]) << 16);
  *(v2u32*)((unsigned short*)dst + idx4) = o;
}

// dst[k*768+c] = src[c*1536+k] (out_w -> owT); 4 strided reads, 8B write
__global__ void transpose_ow_kernel(const float* __restrict__ src, bf16* __restrict__ dst) {
  int idx4 = (blockIdx.x * 256 + threadIdx.x) * 4;
  int k = idx4 / DMODEL, c0 = idx4 % DMODEL;
  unsigned short u[4];
#pragma unroll
  for (int i = 0; i < 4; i++)
    u[i] = f2us(src[(size_t)(c0 + i) * DINNER + k]);
  v2u32 o;
  o[0] = (unsigned int)u[0] | ((unsigned int)u[1] << 16);
  o[1] = (unsigned int)u[2] | ((unsigned int)u[3] << 16);
  *(v2u32*)((unsigned short*)dst + idx4) = o;
}

// ------- bf16 MFMA GEMM, LDS-staged, double-buffered: C[M,N]=A[M,K]@B[N,K]^T -------
// 128x128 tile, BK=32. Per k-step: issue next tile's 4 async16 into buf^1,
// ds_read+MFMA from buf, ONE __syncthreads (its vmcnt/lgkm drain covers the
// staged loads AFTER compute hid their latency). Natural block order (no
// swizzle) keeps per-XCD A working set L2-resident.
// flip_a: per-lane global row reversal (free). Epilogue: bias/flip_c/accum.
template <bool OUT_BF16>
__global__ __launch_bounds__(256) void gemm_lds(
    const bf16* __restrict__ A, const bf16* __restrict__ B, void* __restrict__ C,
    int K, int ldc, int flip_a, int flip_c, int accum, const float* __restrict__ bias) {
  __shared__ unsigned short sA[2 * GBUF];
  __shared__ unsigned short sB[2 * GBUF];
  int tid = threadIdx.x;
  int wave = tid >> 6, lane = tid & 63;
  int l15 = lane & 15, quad = lane >> 4;
  int m0 = blockIdx.x * 128, n0 = blockIdx.y * 128;
  int mw = (wave >> 1) * 64, nw = (wave & 1) * 64;

  // staging addresses: wave w owns rows [w*32, w*32+32) of each tile
  int srow = wave * 32 + (lane >> 2);
  int scol = (lane & 3) * 8;
  const unsigned short* Ap = (const unsigned short*)A;
  const unsigned short* Bp = (const unsigned short*)B;
  int ar0 = m0 + srow, ar1 = m0 + srow + 16;
  if (flip_a) { ar0 = flip_row(ar0); ar1 = flip_row(ar1); }
  const unsigned short* ga0 = Ap + (size_t)ar0 * K + scol;
  const unsigned short* ga1 = Ap + (size_t)ar1 * K + scol;
  const unsigned short* gb0 = Bp + (size_t)(n0 + srow) * K + scol;
  const unsigned short* gb1 = Bp + (size_t)(n0 + srow + 16) * K + scol;
  int lo0 = (wave * 32) * 32;          // wave-uniform LDS offsets (shorts)
  int lo1 = (wave * 32 + 16) * 32;

  v4f acc[4][4];
#pragma unroll
  for (int i = 0; i < 4; i++)
#pragma unroll
    for (int j = 0; j < 4; j++) acc[i][j] = {0.f, 0.f, 0.f, 0.f};

  // prologue: stage k-step 0 into buffer 0
  async16(ga0, &sA[lo0]);
  async16(ga1, &sA[lo1]);
  async16(gb0, &sB[lo0]);
  async16(gb1, &sB[lo1]);
  __syncthreads();

  int nt = K >> 5;
  for (int t = 0; t < nt; t++) {
    int cur = (t & 1) * GBUF;
    if (t + 1 < nt) {           // issue next tile into the other buffer
      int k0 = (t + 1) << 5;
      int nx = ((t + 1) & 1) * GBUF;
      async16(ga0 + k0, &sA[nx + lo0]);
      async16(ga1 + k0, &sA[nx + lo1]);
      async16(gb0 + k0, &sB[nx + lo0]);
      async16(gb1 + k0, &sB[nx + lo1]);
    }
    v8s af[4], bfr[4];
#pragma unroll
    for (int i = 0; i < 4; i++)
      af[i] = *(const v8s*)&sA[cur + (mw + i * 16 + l15) * 32 + quad * 8];
#pragma unroll
    for (int j = 0; j < 4; j++)
      bfr[j] = *(const v8s*)&sB[cur + (nw + j * 16 + l15) * 32 + quad * 8];
#pragma unroll
    for (int i = 0; i < 4; i++)
#pragma unroll
      for (int j = 0; j < 4; j++)
        acc[i][j] = __builtin_amdgcn_mfma_f32_16x16x32_bf16(af[i], bfr[j], acc[i][j], 0, 0, 0);
    __syncthreads();  // drains vmcnt (next tile staged) + protects buf reuse
  }

  float bv[4];
#pragma unroll
  for (int j = 0; j < 4; j++) bv[j] = bias ? bias[n0 + nw + j * 16 + l15] : 0.f;

#pragma unroll
  for (int i = 0; i < 4; i++) {
#pragma unroll
    for (int r2 = 0; r2 < 4; r2++) {
      int row = m0 + mw + i * 16 + quad * 4 + r2;
      int orow = flip_c ? flip_row(row) : row;
#pragma unroll
      for (int j = 0; j < 4; j++) {
        int col = n0 + nw + j * 16 + l15;
        float v = acc[i][j][r2] + bv[j];
        size_t off = (size_t)orow * ldc + col;
        if (OUT_BF16) {
          ((bf16*)C)[off] = __float2bfloat16(v);
        } else {
          float* Cf = (float*)C;
          if (accum) v += Cf[off];
          Cf[off] = v;
        }
      }
    }
  }
}

// ---------------- fused fp32 dt path (both directions, one x pass) ----------------
// C[16384,48] = x[16384,768] @ W[48,768]^T, W = dt rows of in_w (fwd|bwd).
// Grid (128,2): blockIdx.y = dir. Block: 128 tokens x 24 cols, 256 threads;
// thread = (tok2 = lane, cg = 6-col group) owns tokens {base+tok2, base+64+tok2}
// so each sW read feeds 8 FMAs. acc[2][6] only -> no spill. Single-buffered LDS,
// direct global->LDS staging, unroll pinned (kc: 1, k4: 2) so the scheduler
// cannot hoist a chunk's worth of loads into registers (the round-1 spill).
__global__ __launch_bounds__(256) void dt_fused_kernel(
    const float* __restrict__ x,
    const float* __restrict__ in_w0, const float* __restrict__ in_w1,
    const float* __restrict__ dt_bias0, const float* __restrict__ dt_bias1,
    const float* __restrict__ A_log0, const float* __restrict__ A_log1,
    float* __restrict__ dt0, float* __restrict__ dl0,
    float* __restrict__ dt1, float* __restrict__ dl1) {
  __shared__ float sXT[64][128];  // [k][token] transposed
  __shared__ float sW[24][64];    // [col][k]
  int tid = threadIdx.x;
  int tok2 = tid & 63, cg = tid >> 6;   // cg owns cols [cg*6, cg*6+6)
  int dir = blockIdx.y;
  int tok_base = blockIdx.x * 128;

  // staging: 2 threads per token, 32 consecutive k-floats each (8x v4f)
  int st_tok = tid >> 1, st_k0 = (tid & 1) * 32;
  const float* xg = x + (size_t)(tok_base + st_tok) * DMODEL + st_k0;
  const float* wb = dir ? in_w1 : in_w0;
  const float* wrow = wb + (size_t)NROWS_XBC * DMODEL;

  float acc0[6], acc1[6];
#pragma unroll
  for (int c = 0; c < 6; c++) { acc0[c] = 0.f; acc1[c] = 0.f; }

#pragma unroll 1
  for (int kc = 0; kc < 12; kc++) {   // 768 / 64
#pragma unroll
    for (int i = 0; i < 8; i++) {
      v4f v = *(const v4f*)(xg + kc * 64 + i * 4);
#pragma unroll
      for (int j = 0; j < 4; j++) sXT[st_k0 + i * 4 + j][st_tok] = v[j];
    }
    for (int i = tid; i < 24 * 16; i += 256) {
      int col = i >> 4, k4 = i & 15;
      *(v4f*)&sW[col][k4 * 4] =
          *(const v4f*)(wrow + (size_t)col * DMODEL + kc * 64 + k4 * 4);
    }
    __syncthreads();
#pragma unroll 2
    for (int k4 = 0; k4 < 16; k4++) {
      float xa[4], xb[4];
#pragma unroll
      for (int j = 0; j < 4; j++) {
        xa[j] = sXT[k4 * 4 + j][tok2];
        xb[j] = sXT[k4 * 4 + j][tok2 + 64];
      }
#pragma unroll
      for (int c = 0; c < 6; c++) {
        v4f wv = *(const v4f*)&sW[cg * 6 + c][k4 * 4];
#pragma unroll
        for (int j = 0; j < 4; j++) {
          acc0[c] = fmaf(xa[j], wv[j], acc0[c]);
          acc1[c] = fmaf(xb[j], wv[j], acc1[c]);
        }
      }
    }
    __syncthreads();
  }

  // epilogue: exact fp32 softplus / decay (identical formulas to old dt_kernel)
  const float* dtB = dir ? dt_bias1 : dt_bias0;
  const float* Alg = dir ? A_log1 : A_log0;
  float* dto = dir ? dt1 : dt0;
  float* dlo = dir ? dl1 : dl0;
#pragma unroll
  for (int t = 0; t < 2; t++) {
    int r = tok_base + t * 64 + tok2;
    size_t row = dir ? (size_t)flip_row(r) : (size_t)r;
#pragma unroll
    for (int c = 0; c < 6; c++) {
      int h = cg * 6 + c;
      float v = (t ? acc1[c] : acc0[c]) + dtB[h];
      float dtv = (v > 20.f) ? v : log1pf(expf(v));
      dto[row * HN + h] = dtv;
      dlo[row * HN + h] = -dtv * expf(Alg[h]);
    }
  }
}

// ---------------- conv+silu for B/C channels -> per-chunk blobs ----------------
// Thread = (token, 8-channel octet): 4x v8u taps, 8 outputs, one 16B store.
__global__ void conv_bc_kernel(const bf16* __restrict__ xbcr,
                               const float* __restrict__ conv_w,
                               const float* __restrict__ conv_b,
                               bf16* __restrict__ Bblob, bf16* __restrict__ Cblob) {
  int idx = blockIdx.x * 256 + threadIdx.x;  // NTOK*16
  int token = idx >> 4, oct = idx & 15;
  int b = token >> 12, l = token & 4095, c = l >> 6, s = l & 63;
  int ch0 = 1536 + oct * 8;
  const unsigned short* xp = (const unsigned short*)xbcr;
  v8u tv[4];
#pragma unroll
  for (int j = 0; j < 4; j++) {
    int ls = l - 3 + j;
    v8u z = {0, 0, 0, 0, 0, 0, 0, 0};
    tv[j] = z;
    if (ls >= 0)
      tv[j] = *(const v8u*)(xp + (size_t)((b << 12) | ls) * CONVDIM + ch0);
  }
  v8u ov;
#pragma unroll
  for (int e = 0; e < 8; e++) {
    int ch = ch0 + e;
    const float* w4 = conv_w + ch * 4;
    float acc = conv_b[ch];
#pragma unroll
    for (int j = 0; j < 4; j++) acc += us2f(tv[j][e]) * w4[j];
    ov[e] = f2us(acc / (1.f + __expf(-acc)));
  }
  size_t base = ((size_t)((b * 64 + c) * 64 + s)) * 64;
  int ch7 = oct * 8;
  if (ch7 < 64) *(v8u*)((unsigned short*)Bblob + base + ch7) = ov;
  else          *(v8u*)((unsigned short*)Cblob + base + ch7 - 64) = ov;
}

// ---------------- chunked SSD: intra-chunk kernel (MFMA) ----------------
// Round-7: conv taps loaded direct global->registers at kernel top (T14
// issue-early; latency hides under B/C staging + decay scan). The rawX LDS
// staging detour (536 x 16B global->LDS->LDS-read) is gone.
__global__ __launch_bounds__(256) void chunk_intra_kernel(
    const bf16* __restrict__ xbcr, const bf16* __restrict__ Bblob,
    const bf16* __restrict__ Cblob, const float* __restrict__ conv_w,
    const float* __restrict__ conv_b, const float* __restrict__ dtb,
    const float* __restrict__ dlb, const float* __restrict__ Dp,
    bf16* __restrict__ Yblob, bf16* __restrict__ Gblob, float* __restrict__ laq) {
  int blk = blockIdx.x;
  int c = blk & 63, bh = blk >> 6;
  int h = bh % HN, b = bh / HN;
  int tid = threadIdx.x, lane = tid & 63, wv = tid >> 6;
  int l15 = lane & 15, quad = lane >> 4;
  int tok0 = b * SEQL + c * 64;

  __shared__ unsigned short sXT[64][LS];  // [p][s]
  __shared__ unsigned short sB [64][LS];  // [s][n]; later sY [t][p]
  __shared__ unsigned short sBT[64][LS];  // [n][s] dG-scaled
  __shared__ unsigned short sC [64][LS];  // [t][n]; later sG [p][n]
  __shared__ unsigned short sW [64][LS];  // [t][s] decay-masked scores
  __shared__ float sla[64], sdt[64], sdG[64];

  // T14 issue-early: this thread's conv taps (2 octets x 4 rows) direct from
  // global. L2-hot: all 24 h-blocks of a (b,c) group land on the same XCD
  // (blk%8 == c%8; h shifts blk by 64h which is 0 mod 8).
  int s = lane;
  v8u tap0[4], tap1[4];
  {
    const unsigned short* xrow =
        (const unsigned short*)xbcr + (size_t)b * SEQL * CONVDIM + h * 64;
    int p0a = (wv * 2) * 8, p0b = (wv * 2 + 1) * 8;
#pragma unroll
    for (int j = 0; j < 4; j++) {
      int l = c * 64 + s + j - 3;
      v8u z = {0, 0, 0, 0, 0, 0, 0, 0};
      tap0[j] = z;
      tap1[j] = z;
      if (l >= 0) {
        const unsigned short* rp = xrow + (size_t)l * CONVDIM;
        tap0[j] = *(const v8u*)(rp + p0a);
        tap1[j] = *(const v8u*)(rp + p0b);
      }
    }
  }
  {
    const v8u* gB = (const v8u*)((const unsigned short*)Bblob + ((size_t)(b * 64 + c)) * 4096);
    const v8u* gC = (const v8u*)((const unsigned short*)Cblob + ((size_t)(b * 64 + c)) * 4096);
    int r0 = tid >> 3, g0 = tid & 7;
#pragma unroll
    for (int it = 0; it < 2; it++) {
      int row = r0 + it * 32;
      *(v8u*)&sB[row][g0 * 8] = gB[row * 8 + g0];
      *(v8u*)&sC[row][g0 * 8] = gC[row * 8 + g0];
    }
  }
  if (wv == 0) {  // log-decay prefix scan
    float dtv = dtb[(size_t)(tok0 + lane) * HN + h];
    float lg = dlb[(size_t)(tok0 + lane) * HN + h];
#pragma unroll
    for (int d = 1; d < 64; d <<= 1) {
      float o = __shfl_up(lg, d);
      if (lane >= d) lg += o;
    }
    sla[lane] = lg;
    sdt[lane] = dtv;
    float la63 = __shfl(lg, 63);
    sdG[lane] = __expf(la63 - lg) * dtv;
    if (lane == 63) laq[blk] = __expf(la63);
  }
  __syncthreads();

  float Dh = Dp[h];
  {
    // conv+silu from registers: wave wv owns p in [wv*16, wv*16+16)
#pragma unroll
    for (int o = 0; o < 2; o++) {
      int p0 = (wv * 2 + o) * 8;
#pragma unroll
      for (int pp = 0; pp < 8; pp++) {
        int ch = h * 64 + p0 + pp;
        const float* w4 = conv_w + ch * 4;
        float acc = conv_b[ch];
        if (o == 0) {
          acc += us2f(tap0[0][pp]) * w4[0] + us2f(tap0[1][pp]) * w4[1] +
                 us2f(tap0[2][pp]) * w4[2] + us2f(tap0[3][pp]) * w4[3];
        } else {
          acc += us2f(tap1[0][pp]) * w4[0] + us2f(tap1[1][pp]) * w4[1] +
                 us2f(tap1[2][pp]) * w4[2] + us2f(tap1[3][pp]) * w4[3];
        }
        sXT[p0 + pp][s] = f2us(acc / (1.f + __expf(-acc)));
      }
    }
#pragma unroll
    for (int it = 0; it < 16; it++) {
      int n = wv + it * 4;
      sBT[n][s] = f2us(us2f(sB[s][n]) * sdG[s]);
    }
  }
  __syncthreads();

  {  // W = C @ B^T, masked decay
    v4f acc[4];
#pragma unroll
    for (int j = 0; j < 4; j++) acc[j] = {0.f, 0.f, 0.f, 0.f};
    __builtin_amdgcn_s_setprio(1);
#pragma unroll
    for (int k0 = 0; k0 < 2; k0++) {
      v8s a = *(const v8s*)&sC[16 * wv + l15][k0 * 32 + quad * 8];
#pragma unroll
      for (int j = 0; j < 4; j++) {
        v8s bb = *(const v8s*)&sB[16 * j + l15][k0 * 32 + quad * 8];
        acc[j] = __builtin_amdgcn_mfma_f32_16x16x32_bf16(a, bb, acc[j], 0, 0, 0);
      }
    }
    __builtin_amdgcn_s_setprio(0);
    float lat[4];
#pragma unroll
    for (int r = 0; r < 4; r++) lat[r] = sla[16 * wv + quad * 4 + r];
#pragma unroll
    for (int j = 0; j < 4; j++) {
      int sc = 16 * j + l15;
      float las = sla[sc], dts = sdt[sc];
#pragma unroll
      for (int r = 0; r < 4; r++) {
        int t = 16 * wv + quad * 4 + r;
        float w = (sc <= t) ? __expf(lat[r] - las) * dts * acc[j][r] : 0.f;
        sW[t][sc] = f2us(w);
      }
    }
  }
  __syncthreads();

  {  // y = W @ X + D*x; G = X @ BT
    v4f ya[4], ga[4];
#pragma unroll
    for (int j = 0; j < 4; j++) {
      ya[j] = {0.f, 0.f, 0.f, 0.f};
      ga[j] = {0.f, 0.f, 0.f, 0.f};
    }
    __builtin_amdgcn_s_setprio(1);
#pragma unroll
    for (int k0 = 0; k0 < 2; k0++) {
      v8s aw = *(const v8s*)&sW[16 * wv + l15][k0 * 32 + quad * 8];
      v8s ax = *(const v8s*)&sXT[16 * wv + l15][k0 * 32 + quad * 8];
#pragma unroll
      for (int j = 0; j < 4; j++) {
        v8s bx = *(const v8s*)&sXT[16 * j + l15][k0 * 32 + quad * 8];
        v8s bt = *(const v8s*)&sBT[16 * j + l15][k0 * 32 + quad * 8];
        ya[j] = __builtin_amdgcn_mfma_f32_16x16x32_bf16(aw, bx, ya[j], 0, 0, 0);
        ga[j] = __builtin_amdgcn_mfma_f32_16x16x32_bf16(ax, bt, ga[j], 0, 0, 0);
      }
    }
    __builtin_amdgcn_s_setprio(0);
#pragma unroll
    for (int j = 0; j < 4; j++) {
      int col = 16 * j + l15;
#pragma unroll
      for (int r = 0; r < 4; r++) {
        int row = 16 * wv + quad * 4 + r;
        float yv = ya[j][r] + Dh * us2f(sXT[col][row]);
        sB[row][col] = f2us(yv);
        sC[row][col] = f2us(ga[j][r]);
      }
    }
  }
  __syncthreads();

  {  // blob out: 2 passes of 16B
    v8u* gY = (v8u*)(Yblob + (size_t)blk * 4096);
    v8u* gG = (v8u*)(Gblob + (size_t)blk * 4096);
#pragma unroll
    for (int it = 0; it < 2; it++) {
      int i = tid + it * 256;
      int row = i >> 3, j = i & 7;
      gY[row * 8 + j] = *(const v8u*)&sB[row][j * 8];
      gG[row * 8 + j] = *(const v8u*)&sC[row][j * 8];
    }
  }
}

// ---------------- chunked SSD: inter-chunk state recurrence ----------------
__global__ __launch_bounds__(256) void state_scan_kernel(
    bf16* __restrict__ blob, const float* __restrict__ laq) {
  int bh = blockIdx.x;
  int tid = threadIdx.x;
  size_t base = (size_t)bh * 64 * 4096 + (size_t)(tid >> 2) * 64 + (size_t)(tid & 3) * 16;
  float S[16];
#pragma unroll
  for (int i = 0; i < 16; i++) S[i] = 0.f;
  for (int c = 0; c < 64; c++) {
    float q = laq[bh * 64 + c];
    unsigned short* gp = (unsigned short*)blob + base + (size_t)c * 4096;
    v8u ga = ((v8u*)gp)[0], gb = ((v8u*)gp)[1];
    v8u pa, pb;
#pragma unroll
    for (int i = 0; i < 8; i++) {
      pa[i] = f2us(S[i]);
      pb[i] = f2us(S[8 + i]);
    }
    ((v8u*)gp)[0] = pa;
    ((v8u*)gp)[1] = pb;
#pragma unroll
    for (int i = 0; i < 8; i++) {
      S[i] = q * S[i] + us2f(ga[i]);
      S[8 + i] = q * S[8 + i] + us2f(gb[i]);
    }
  }
}

// ---------------- chunked SSD: inter-chunk y contribution (MFMA) ----------------
__global__ __launch_bounds__(256) void chunk_inter_kernel(
    const bf16* __restrict__ Cblob, const float* __restrict__ dlb,
    const bf16* __restrict__ blob, bf16* __restrict__ Yblob) {
  int blk = blockIdx.x;
  int c = blk & 63, bh = blk >> 6;
  int h = bh % HN, b = bh / HN;
  int tid = threadIdx.x, lane = tid & 63, wv = tid >> 6;
  int l15 = lane & 15, quad = lane >> 4;
  int tok0 = b * SEQL + c * 64;

  __shared__ unsigned short sC[64][LS];
  __shared__ unsigned short sY[64][LS];
  __shared__ float sel[64];

  {
    const v8u* gC = (const v8u*)((const unsigned short*)Cblob + ((size_t)(b * 64 + c)) * 4096);
    int r0 = tid >> 3, g0 = tid & 7;
#pragma unroll
    for (int it = 0; it < 2; it++) {
      int row = r0 + it * 32;
      *(v8u*)&sC[row][g0 * 8] = gC[row * 8 + g0];
    }
  }
  if (wv == 0) {
    float lg = dlb[(size_t)(tok0 + lane) * HN + h];
#pragma unroll
    for (int d = 1; d < 64; d <<= 1) {
      float o = __shfl_up(lg, d);
      if (lane >= d) lg += o;
    }
    sel[lane] = __expf(lg);
  }
  __syncthreads();
  {
    v4f acc[4];
#pragma unroll
    for (int j = 0; j < 4; j++) acc[j] = {0.f, 0.f, 0.f, 0.f};
    const unsigned short* gS = (const unsigned short*)blob + (size_t)blk * 4096;
    __builtin_amdgcn_s_setprio(1);
#pragma unroll
    for (int k0 = 0; k0 < 2; k0++) {
      v8s a = *(const v8s*)&sC[16 * wv + l15][k0 * 32 + quad * 8];
#pragma unroll
      for (int j = 0; j < 4; j++) {
        v8s bS = *(const v8s*)(gS + (size_t)(16 * j + l15) * 64 + k0 * 32 + quad * 8);
        acc[j] = __builtin_amdgcn_mfma_f32_16x16x32_bf16(a, bS, acc[j], 0, 0, 0);
      }
    }
    __builtin_amdgcn_s_setprio(0);
    float selt[4];
#pragma unroll
    for (int r = 0; r < 4; r++) selt[r] = sel[16 * wv + quad * 4 + r];
#pragma unroll
    for (int j = 0; j < 4; j++)
#pragma unroll
      for (int r = 0; r < 4; r++)
        sY[16 * wv + quad * 4 + r][16 * j + l15] = f2us(selt[r] * acc[j][r]);
  }
  __syncthreads();
  {  // Y RMW: 2 passes of 16B
    v8u* gY = (v8u*)(Yblob + (size_t)blk * 4096);
#pragma unroll
    for (int it = 0; it < 2; it++) {
      int i = tid + it * 256;
      int row = i >> 3, j = i & 7;
      v8u old = gY[row * 8 + j];
      v8u add = *(const v8u*)&sY[row][j * 8];
      v8u outv;
#pragma unroll
      for (int e = 0; e < 8; e++) outv[e] = f2us(us2f(old[e]) + us2f(add[e]));
      gY[row * 8 + j] = outv;
    }
  }
}

// ---------------- gated RMSNorm: blob y + z rows -> ynorm rows ----------------
// Paired (4B) loads/stores: 3 iterations of 2 channels.
__global__ __launch_bounds__(256) void norm_kernel(
    const bf16* __restrict__ Yblob, const bf16* __restrict__ z,
    const float* __restrict__ norm_w, bf16* __restrict__ out) {
  int token = blockIdx.x;
  int tid = threadIdx.x;
  int b = token >> 12, l = token & 4095, c = l >> 6, t = l & 63;
  const unsigned short* zp = (const unsigned short*)z + (size_t)token * DINNER;
  float vals[6];
  float ss = 0.f;
#pragma unroll
  for (int i = 0; i < 3; i++) {
    int q = tid + i * 256;          // pair index 0..767
    int ch = q * 2;
    int hh = ch >> 6, p = ch & 63;  // p even
    size_t yi = ((((size_t)(b * HN + hh)) * 64 + c) * 64 + t) * 64 + p;
    unsigned int yv2 = *(const unsigned int*)((const unsigned short*)Yblob + yi);
    unsigned int zv2 = *(const unsigned int*)(zp + ch);
#pragma unroll
    for (int e = 0; e < 2; e++) {
      float yv = us2f((unsigned short)((yv2 >> (16 * e)) & 0xffff));
      float zv = us2f((unsigned short)((zv2 >> (16 * e)) & 0xffff));
      float g = zv / (1.f + __expf(-zv));
      float v = yv * g;
      vals[i * 2 + e] = v;
      ss += v * v;
    }
  }
  for (int off = 32; off > 0; off >>= 1) ss += __shfl_down(ss, off);
  __shared__ float sred[4];
  if ((tid & 63) == 0) sred[tid >> 6] = ss;
  __syncthreads();
  float tot = sred[0] + sred[1] + sred[2] + sred[3];
  float scale = rsqrtf(tot / (float)DINNER + 1e-5f);
#pragma unroll
  for (int i = 0; i < 3; i++) {
    int q = tid + i * 256;
    int ch = q * 2;
    unsigned int o =
        (unsigned int)f2us(vals[i * 2] * scale * norm_w[ch]) |
        ((unsigned int)f2us(vals[i * 2 + 1] * scale * norm_w[ch + 1]) << 16);
    *(unsigned int*)((unsigned short*)out + (size_t)token * DINNER + ch) = o;
  }
}

// ---------------- launch ----------------
extern "C" void kernel_launch(void* const* d_in, const int* in_sizes, int n_in,
                              void* d_out, int out_size, void* d_ws, size_t ws_size,
                              hipStream_t stream) {
  const float* x = (const float*)d_in[0];
  const float* fus_w = (const float*)d_in[1];
  const float* fus_b = (const float*)d_in[2];
  const float* in_w[2] = {(const float*)d_in[3], (const float*)d_in[11]};
  const float* conv_w[2] = {(const float*)d_in[4], (const float*)d_in[12]};
  const float* conv_b[2] = {(const float*)d_in[5], (const float*)d_in[13]};
  const float* dt_bias[2] = {(const float*)d_in[6], (const float*)d_in[14]};
  const float* A_log[2] = {(const float*)d_in[7], (const float*)d_in[15]};
  const float* Dp[2] = {(const float*)d_in[8], (const float*)d_in[16]};
  const float* norm_w[2] = {(const float*)d_in[9], (const float*)d_in[17]};
  const float* out_w[2] = {(const float*)d_in[10], (const float*)d_in[18]};
  (void)in_sizes; (void)n_in;

  char* ws = (char*)d_ws;
  size_t off = 0;
  auto alloc = [&](size_t bytes) {
    size_t o = off;
    off = (off + bytes + 255) & ~(size_t)255;
    return o;
  };
  bf16* x_bf  = (bf16*)(ws + alloc((size_t)NTOK * DMODEL * 2));          // 25.2 MB
  bf16* w_in  = (bf16*)(ws + alloc((size_t)NROWS_XBC * DMODEL * 2));     //  4.9 MB
  bf16* wf1   = (bf16*)(ws + alloc((size_t)DMODEL * DMODEL * 2));        //  1.2 MB
  bf16* owT   = (bf16*)(ws + alloc((size_t)DINNER * DMODEL * 2));        //  2.4 MB
  bf16* wc    = (bf16*)(ws + alloc((size_t)DMODEL * DINNER * 2));        //  2.4 MB
  bf16* xbcr  = (bf16*)(ws + alloc((size_t)NTOK * CONVDIM * 2));         // 54.5 MB (ynorm aliases)
  float* dtb0 = (float*)(ws + alloc((size_t)NTOK * HN * 4));             //  1.6 MB
  float* dlb0 = (float*)(ws + alloc((size_t)NTOK * HN * 4));             //  1.6 MB
  float* dtb1 = (float*)(ws + alloc((size_t)NTOK * HN * 4));             //  1.6 MB
  float* dlb1 = (float*)(ws + alloc((size_t)NTOK * HN * 4));             //  1.6 MB
  float* laq  = (float*)(ws + alloc((size_t)BATCHN * HN * NCHUNK * 4));  //  0.02 MB
  bf16* Bblob = (bf16*)(ws + alloc((size_t)NTOK * DSTATE * 2));          //  2.1 MB
  bf16* Cblob = (bf16*)(ws + alloc((size_t)NTOK * DSTATE * 2));          //  2.1 MB
  bf16* Gblob = (bf16*)(ws + alloc((size_t)NTOK * DINNER * 2));          // 50.3 MB (z aliases)
  bf16* Yblob = (bf16*)(ws + alloc((size_t)NTOK * DINNER * 2));          // 50.3 MB
  bf16* zbuf  = Gblob;  // z GEMM output reuses G/prefix blob (dead after chunk_inter)
  bf16* ynorm = xbcr;   // normalized y reuses xbcr (dead after chunk_inter)
  float* dtbs[2] = {dtb0, dtb1};
  float* dlbs[2] = {dlb0, dlb1};

  if (ws_size < off) {  // diagnostic: clean absmax(=max|ref|) failure, not a crash
    hipMemsetAsync(d_out, 0, (size_t)out_size * 4, stream);
    return;
  }

  cast_x_kernel<<<(NTOK * DMODEL) / 1024, 256, 0, stream>>>(x, x_bf);
  // exact fp32 dt + log-decay, both directions in one x pass
  dt_fused_kernel<<<dim3(NTOK / 128, 2), 256, 0, stream>>>(
      x, in_w[0], in_w[1], dt_bias[0], dt_bias[1], A_log[0], A_log[1],
      dtb0, dlb0, dtb1, dlb1);

  for (int dir = 0; dir < 2; dir++) {
    cast_kernel<<<(NROWS_XBC * DMODEL) / 1024, 256, 0, stream>>>(in_w[dir], w_in);
    // in-proj xBC part (in_w rows 1536..3200) -> xbcr
    gemm_lds<true><<<dim3(NTOK / 128, CONVDIM / 128), 256, 0, stream>>>(
        x_bf, w_in + (size_t)DINNER * DMODEL, xbcr, DMODEL, CONVDIM, dir, 0, 0, nullptr);
    // B/C conv+silu once -> per-chunk blobs
    conv_bc_kernel<<<(NTOK * 16) / 256, 256, 0, stream>>>(
        xbcr, conv_w[dir], conv_b[dir], Bblob, Cblob);
    // chunked SSD
    chunk_intra_kernel<<<BATCHN * HN * NCHUNK, 256, 0, stream>>>(
        xbcr, Bblob, Cblob, conv_w[dir], conv_b[dir], dtbs[dir], dlbs[dir], Dp[dir],
        Yblob, Gblob, laq);
    state_scan_kernel<<<BATCHN * HN, 256, 0, stream>>>(Gblob, laq);
    chunk_inter_kernel<<<BATCHN * HN * NCHUNK, 256, 0, stream>>>(Cblob, dlbs[dir], Gblob, Yblob);
    // in-proj z part (in_w rows 0..1536) -> zbuf (blob region, now dead)
    gemm_lds<true><<<dim3(NTOK / 128, DINNER / 128), 256, 0, stream>>>(
        x_bf, w_in, zbuf, DMODEL, DINNER, dir, 0, 0, nullptr);
    // gated RMSNorm -> ynorm rows (xbcr region, now dead)
    norm_kernel<<<NTOK, 256, 0, stream>>>(Yblob, zbuf, norm_w[dir], ynorm);
    // combined weight wc = fus_half @ out_w  (768x1536)
    cast_strided_kernel<<<(DMODEL * DMODEL) / 1024, 256, 0, stream>>>(
        fus_w + dir * DMODEL, wf1, DMODEL, 2 * DMODEL);
    transpose_ow_kernel<<<(DINNER * DMODEL) / 1024, 256, 0, stream>>>(out_w[dir], owT);
    gemm_lds<true><<<dim3(DMODEL / 128, DINNER / 128), 256, 0, stream>>>(
        wf1, owT, wc, DMODEL, DINNER, 0, 0, 0, nullptr);
    // out-proj + fusion: d_out (+)= ynorm @ wc^T (dir1 un-flips rows, accumulates)
    gemm_lds<false><<<dim3(NTOK / 128, DMODEL / 128), 256, 0, stream>>>(
        ynorm, wc, d_out, DINNER, DMODEL, 0, dir, dir, dir == 0 ? fus_b : nullptr);
  }
}

// Round 8
// 914.458 us; speedup vs baseline: 1.0288x; 1.0288x over previous
//
#include <hip/hip_runtime.h>
#include <hip/hip_bf16.h>

// BiMamba: bidirectional Mamba2 forward, MI355X/gfx950.
// Per direction: in-proj (bf16 MFMA GEMM, A-row flip for backward) -> exact
// fp32 dt/log-decay (fused both-dir tiled GEMV) -> conv+silu for B/C once into
// per-chunk blobs -> chunked SSD scan (three 64^3 matmuls on MFMA) -> z GEMM
// -> gated RMSNorm -> combined out-proj+fusion GEMM into fp32 d_out.
// GEMM (round-5 form, measured best): 128x128 tile, BK=32, async global->LDS
// (16B), DOUBLE-buffered LDS with ONE barrier per k-step. Round-6 A/B showed
// counted-vmcnt 3-buf is null; round-4 showed XCD swizzle breaks the natural
// x-major L2 residency (xcd = blockIdx.x%8 -> per-XCD A set is 3.1 MB).
// Round-8: chunk_intra back to r5 rawX-LDS staging (r7's per-lane direct tap
// loads were 64-line uncoalesced, +22 us); state_scan split 4x per (b,h) so
// all 256 CUs participate (was 96 blocks -> 96 CUs).
// Round-3: all scalar memory paths in the SSD chain vectorized to 16B (G13).

#define BATCHN 4
#define SEQL 4096
#define DMODEL 768
#define DINNER 1536
#define DSTATE 64
#define HN 24
#define CONVDIM 1664          // DINNER + 2*DSTATE
#define NROWS_XBC 3200        // DINNER + CONVDIM (in_w rows GEMMed; dt rows excluded)
#define NTOK (BATCHN*SEQL)    // 16384
#define NCHUNK 64             // SEQL / 64
#define LS 72                 // LDS stride (shorts) for chunk kernels
#define GBUF (128 * 32)       // one GEMM LDS buffer (shorts)

typedef short v8s __attribute__((ext_vector_type(8)));
typedef unsigned short v8u __attribute__((ext_vector_type(8)));
typedef unsigned short v4u __attribute__((ext_vector_type(4)));
typedef float v4f __attribute__((ext_vector_type(4)));
typedef unsigned int v2u32 __attribute__((ext_vector_type(2)));
typedef __hip_bfloat16 bf16;

__device__ __forceinline__ int flip_row(int r) {
  return (r & ~4095) | (4095 - (r & 4095));
}
__device__ __forceinline__ float us2f(unsigned short u) {
  return __uint_as_float(((unsigned int)u) << 16);
}
__device__ __forceinline__ unsigned short f2us(float f) {
  bf16 b = __float2bfloat16(f);
  return __builtin_bit_cast(unsigned short, b);
}
// async 16B/lane global->LDS; LDS dest = wave-uniform base + lane*16
__device__ __forceinline__ void async16(const unsigned short* g, unsigned short* l) {
  __builtin_amdgcn_global_load_lds(
      (const __attribute__((address_space(1))) unsigned int*)(const void*)g,
      (__attribute__((address_space(3))) unsigned int*)(void*)l, 16, 0, 0);
}

// ---------------- cast kernels (4-wide) ----------------

__global__ void cast_x_kernel(const float* __restrict__ x, bf16* __restrict__ xf) {
  int idx = blockIdx.x * 256 + threadIdx.x;   // x4 elements
  v4f v = *(const v4f*)(x + (size_t)idx * 4);
  v2u32 o;
  o[0] = (unsigned int)f2us(v[0]) | ((unsigned int)f2us(v[1]) << 16);
  o[1] = (unsigned int)f2us(v[2]) | ((unsigned int)f2us(v[3]) << 16);
  *(v2u32*)((unsigned short*)xf + (size_t)idx * 4) = o;
}

__global__ void cast_kernel(const float* __restrict__ src, bf16* __restrict__ dst) {
  int idx = blockIdx.x * 256 + threadIdx.x;   // x4 elements
  v4f v = *(const v4f*)(src + (size_t)idx * 4);
  v2u32 o;
  o[0] = (unsigned int)f2us(v[0]) | ((unsigned int)f2us(v[1]) << 16);
  o[1] = (unsigned int)f2us(v[2]) | ((unsigned int)f2us(v[3]) << 16);
  *(v2u32*)((unsigned short*)dst + (size_t)idx * 4) = o;
}

// dst[j*cols+m] = src[j*src_stride+m]  (extract fus_w half), 4-wide (cols%4==0)
__global__ void cast_strided_kernel(const float* __restrict__ src, bf16* __restrict__ dst,
                                    int cols, int src_stride) {
  int idx4 = (blockIdx.x * 256 + threadIdx.x) * 4;
  int j = idx4 / cols, m = idx4 % cols;
  v4f v = *(const v4f*)(src + (size_t)j * src_stride + m);
  v2u32 o;
  o[0] = (unsigned int)f2us(v[0]) | ((unsigned int)f2us(v[1]) << 16);
  o[1] = (unsigned int)f2us(v[2]) | ((unsigned int)f2us(v[3]) << 16);
  *(v2u32*)((unsigned short*)dst + idx4) = o;
}

// dst[k*768+c] = src[c*1536+k] (out_w -> owT); 4 strided reads, 8B write
__global__ void transpose_ow_kernel(const float* __restrict__ src, bf16* __restrict__ dst) {
  int idx4 = (blockIdx.x * 256 + threadIdx.x) * 4;
  int k = idx4 / DMODEL, c0 = idx4 % DMODEL;
  unsigned short u[4];
#pragma unroll
  for (int i = 0; i < 4; i++)
    u[i] = f2us(src[(size_t)(c0 + i) * DINNER + k]);
  v2u32 o;
  o[0] = (unsigned int)u[0] | ((unsigned int)u[1] << 16);
  o[1] = (unsigned int)u[2] | ((unsigned int)u[3] << 16);
  *(v2u32*)((unsigned short*)dst + idx4) = o;
}

// ------- bf16 MFMA GEMM, LDS-staged, double-buffered: C[M,N]=A[M,K]@B[N,K]^T -------
// 128x128 tile, BK=32. Per k-step: issue next tile's 4 async16 into buf^1,
// ds_read+MFMA from buf, ONE __syncthreads (its vmcnt/lgkm drain covers the
// staged loads AFTER compute hid their latency). Natural block order (no
// swizzle) keeps per-XCD A working set L2-resident.
// flip_a: per-lane global row reversal (free). Epilogue: bias/flip_c/accum.
template <bool OUT_BF16>
__global__ __launch_bounds__(256) void gemm_lds(
    const bf16* __restrict__ A, const bf16* __restrict__ B, void* __restrict__ C,
    int K, int ldc, int flip_a, int flip_c, int accum, const float* __restrict__ bias) {
  __shared__ unsigned short sA[2 * GBUF];
  __shared__ unsigned short sB[2 * GBUF];
  int tid = threadIdx.x;
  int wave = tid >> 6, lane = tid & 63;
  int l15 = lane & 15, quad = lane >> 4;
  int m0 = blockIdx.x * 128, n0 = blockIdx.y * 128;
  int mw = (wave >> 1) * 64, nw = (wave & 1) * 64;

  // staging addresses: wave w owns rows [w*32, w*32+32) of each tile
  int srow = wave * 32 + (lane >> 2);
  int scol = (lane & 3) * 8;
  const unsigned short* Ap = (const unsigned short*)A;
  const unsigned short* Bp = (const unsigned short*)B;
  int ar0 = m0 + srow, ar1 = m0 + srow + 16;
  if (flip_a) { ar0 = flip_row(ar0); ar1 = flip_row(ar1); }
  const unsigned short* ga0 = Ap + (size_t)ar0 * K + scol;
  const unsigned short* ga1 = Ap + (size_t)ar1 * K + scol;
  const unsigned short* gb0 = Bp + (size_t)(n0 + srow) * K + scol;
  const unsigned short* gb1 = Bp + (size_t)(n0 + srow + 16) * K + scol;
  int lo0 = (wave * 32) * 32;          // wave-uniform LDS offsets (shorts)
  int lo1 = (wave * 32 + 16) * 32;

  v4f acc[4][4];
#pragma unroll
  for (int i = 0; i < 4; i++)
#pragma unroll
    for (int j = 0; j < 4; j++) acc[i][j] = {0.f, 0.f, 0.f, 0.f};

  // prologue: stage k-step 0 into buffer 0
  async16(ga0, &sA[lo0]);
  async16(ga1, &sA[lo1]);
  async16(gb0, &sB[lo0]);
  async16(gb1, &sB[lo1]);
  __syncthreads();

  int nt = K >> 5;
  for (int t = 0; t < nt; t++) {
    int cur = (t & 1) * GBUF;
    if (t + 1 < nt) {           // issue next tile into the other buffer
      int k0 = (t + 1) << 5;
      int nx = ((t + 1) & 1) * GBUF;
      async16(ga0 + k0, &sA[nx + lo0]);
      async16(ga1 + k0, &sA[nx + lo1]);
      async16(gb0 + k0, &sB[nx + lo0]);
      async16(gb1 + k0, &sB[nx + lo1]);
    }
    v8s af[4], bfr[4];
#pragma unroll
    for (int i = 0; i < 4; i++)
      af[i] = *(const v8s*)&sA[cur + (mw + i * 16 + l15) * 32 + quad * 8];
#pragma unroll
    for (int j = 0; j < 4; j++)
      bfr[j] = *(const v8s*)&sB[cur + (nw + j * 16 + l15) * 32 + quad * 8];
#pragma unroll
    for (int i = 0; i < 4; i++)
#pragma unroll
      for (int j = 0; j < 4; j++)
        acc[i][j] = __builtin_amdgcn_mfma_f32_16x16x32_bf16(af[i], bfr[j], acc[i][j], 0, 0, 0);
    __syncthreads();  // drains vmcnt (next tile staged) + protects buf reuse
  }

  float bv[4];
#pragma unroll
  for (int j = 0; j < 4; j++) bv[j] = bias ? bias[n0 + nw + j * 16 + l15] : 0.f;

#pragma unroll
  for (int i = 0; i < 4; i++) {
#pragma unroll
    for (int r2 = 0; r2 < 4; r2++) {
      int row = m0 + mw + i * 16 + quad * 4 + r2;
      int orow = flip_c ? flip_row(row) : row;
#pragma unroll
      for (int j = 0; j < 4; j++) {
        int col = n0 + nw + j * 16 + l15;
        float v = acc[i][j][r2] + bv[j];
        size_t off = (size_t)orow * ldc + col;
        if (OUT_BF16) {
          ((bf16*)C)[off] = __float2bfloat16(v);
        } else {
          float* Cf = (float*)C;
          if (accum) v += Cf[off];
          Cf[off] = v;
        }
      }
    }
  }
}

// ---------------- fused fp32 dt path (both directions, one x pass) ----------------
// C[16384,48] = x[16384,768] @ W[48,768]^T, W = dt rows of in_w (fwd|bwd).
// Grid (128,2): blockIdx.y = dir. Block: 128 tokens x 24 cols, 256 threads;
// thread = (tok2 = lane, cg = 6-col group) owns tokens {base+tok2, base+64+tok2}
// so each sW read feeds 8 FMAs. acc[2][6] only -> no spill. Single-buffered LDS,
// direct global->LDS staging, unroll pinned (kc: 1, k4: 2) so the scheduler
// cannot hoist a chunk's worth of loads into registers (the round-1 spill).
__global__ __launch_bounds__(256) void dt_fused_kernel(
    const float* __restrict__ x,
    const float* __restrict__ in_w0, const float* __restrict__ in_w1,
    const float* __restrict__ dt_bias0, const float* __restrict__ dt_bias1,
    const float* __restrict__ A_log0, const float* __restrict__ A_log1,
    float* __restrict__ dt0, float* __restrict__ dl0,
    float* __restrict__ dt1, float* __restrict__ dl1) {
  __shared__ float sXT[64][128];  // [k][token] transposed
  __shared__ float sW[24][64];    // [col][k]
  int tid = threadIdx.x;
  int tok2 = tid & 63, cg = tid >> 6;   // cg owns cols [cg*6, cg*6+6)
  int dir = blockIdx.y;
  int tok_base = blockIdx.x * 128;

  // staging: 2 threads per token, 32 consecutive k-floats each (8x v4f)
  int st_tok = tid >> 1, st_k0 = (tid & 1) * 32;
  const float* xg = x + (size_t)(tok_base + st_tok) * DMODEL + st_k0;
  const float* wb = dir ? in_w1 : in_w0;
  const float* wrow = wb + (size_t)NROWS_XBC * DMODEL;

  float acc0[6], acc1[6];
#pragma unroll
  for (int c = 0; c < 6; c++) { acc0[c] = 0.f; acc1[c] = 0.f; }

#pragma unroll 1
  for (int kc = 0; kc < 12; kc++) {   // 768 / 64
#pragma unroll
    for (int i = 0; i < 8; i++) {
      v4f v = *(const v4f*)(xg + kc * 64 + i * 4);
#pragma unroll
      for (int j = 0; j < 4; j++) sXT[st_k0 + i * 4 + j][st_tok] = v[j];
    }
    for (int i = tid; i < 24 * 16; i += 256) {
      int col = i >> 4, k4 = i & 15;
      *(v4f*)&sW[col][k4 * 4] =
          *(const v4f*)(wrow + (size_t)col * DMODEL + kc * 64 + k4 * 4);
    }
    __syncthreads();
#pragma unroll 2
    for (int k4 = 0; k4 < 16; k4++) {
      float xa[4], xb[4];
#pragma unroll
      for (int j = 0; j < 4; j++) {
        xa[j] = sXT[k4 * 4 + j][tok2];
        xb[j] = sXT[k4 * 4 + j][tok2 + 64];
      }
#pragma unroll
      for (int c = 0; c < 6; c++) {
        v4f wv = *(const v4f*)&sW[cg * 6 + c][k4 * 4];
#pragma unroll
        for (int j = 0; j < 4; j++) {
          acc0[c] = fmaf(xa[j], wv[j], acc0[c]);
          acc1[c] = fmaf(xb[j], wv[j], acc1[c]);
        }
      }
    }
    __syncthreads();
  }

  // epilogue: exact fp32 softplus / decay (identical formulas to old dt_kernel)
  const float* dtB = dir ? dt_bias1 : dt_bias0;
  const float* Alg = dir ? A_log1 : A_log0;
  float* dto = dir ? dt1 : dt0;
  float* dlo = dir ? dl1 : dl0;
#pragma unroll
  for (int t = 0; t < 2; t++) {
    int r = tok_base + t * 64 + tok2;
    size_t row = dir ? (size_t)flip_row(r) : (size_t)r;
#pragma unroll
    for (int c = 0; c < 6; c++) {
      int h = cg * 6 + c;
      float v = (t ? acc1[c] : acc0[c]) + dtB[h];
      float dtv = (v > 20.f) ? v : log1pf(expf(v));
      dto[row * HN + h] = dtv;
      dlo[row * HN + h] = -dtv * expf(Alg[h]);
    }
  }
}

// ---------------- conv+silu for B/C channels -> per-chunk blobs ----------------
// Thread = (token, 8-channel octet): 4x v8u taps, 8 outputs, one 16B store.
__global__ void conv_bc_kernel(const bf16* __restrict__ xbcr,
                               const float* __restrict__ conv_w,
                               const float* __restrict__ conv_b,
                               bf16* __restrict__ Bblob, bf16* __restrict__ Cblob) {
  int idx = blockIdx.x * 256 + threadIdx.x;  // NTOK*16
  int token = idx >> 4, oct = idx & 15;
  int b = token >> 12, l = token & 4095, c = l >> 6, s = l & 63;
  int ch0 = 1536 + oct * 8;
  const unsigned short* xp = (const unsigned short*)xbcr;
  v8u tv[4];
#pragma unroll
  for (int j = 0; j < 4; j++) {
    int ls = l - 3 + j;
    v8u z = {0, 0, 0, 0, 0, 0, 0, 0};
    tv[j] = z;
    if (ls >= 0)
      tv[j] = *(const v8u*)(xp + (size_t)((b << 12) | ls) * CONVDIM + ch0);
  }
  v8u ov;
#pragma unroll
  for (int e = 0; e < 8; e++) {
    int ch = ch0 + e;
    const float* w4 = conv_w + ch * 4;
    float acc = conv_b[ch];
#pragma unroll
    for (int j = 0; j < 4; j++) acc += us2f(tv[j][e]) * w4[j];
    ov[e] = f2us(acc / (1.f + __expf(-acc)));
  }
  size_t base = ((size_t)((b * 64 + c) * 64 + s)) * 64;
  int ch7 = oct * 8;
  if (ch7 < 64) *(v8u*)((unsigned short*)Bblob + base + ch7) = ov;
  else          *(v8u*)((unsigned short*)Cblob + base + ch7 - 64) = ov;
}

// ---------------- chunked SSD: intra-chunk kernel (MFMA) ----------------
__global__ __launch_bounds__(256) void chunk_intra_kernel(
    const bf16* __restrict__ xbcr, const bf16* __restrict__ Bblob,
    const bf16* __restrict__ Cblob, const float* __restrict__ conv_w,
    const float* __restrict__ conv_b, const float* __restrict__ dtb,
    const float* __restrict__ dlb, const float* __restrict__ Dp,
    bf16* __restrict__ Yblob, bf16* __restrict__ Gblob, float* __restrict__ laq) {
  int blk = blockIdx.x;
  int c = blk & 63, bh = blk >> 6;
  int h = bh % HN, b = bh / HN;
  int tid = threadIdx.x, lane = tid & 63, wv = tid >> 6;
  int l15 = lane & 15, quad = lane >> 4;
  int tok0 = b * SEQL + c * 64;

  __shared__ unsigned short sXT[64][LS];  // [p][s]
  __shared__ unsigned short sB [64][LS];  // [s][n]; later sY [t][p]
  __shared__ unsigned short sBT[64][LS];  // [n][s] dG-scaled
  __shared__ unsigned short sC [64][LS];  // [t][n]; later sG [p][n]
  // rawX stride 72 shorts (144B): v8u rows 16B-aligned; dead before W written
  __shared__ union { unsigned short rawX[67][72]; unsigned short W[64][LS]; } sU;
  __shared__ float sla[64], sdt[64], sdG[64];

  // rawX staging: 67 rows x 8 v8u = 536 16B units (coalesced: 8 thr/row)
  for (int i = tid; i < 536; i += 256) {
    int r = i >> 3, j = i & 7;
    int l = c * 64 + r - 3;
    v8u v = {0, 0, 0, 0, 0, 0, 0, 0};
    if (l >= 0)
      v = *(const v8u*)((const unsigned short*)xbcr +
                        (size_t)(b * SEQL + l) * CONVDIM + h * 64 + j * 8);
    *(v8u*)&sU.rawX[r][j * 8] = v;
  }
  {
    const v8u* gB = (const v8u*)((const unsigned short*)Bblob + ((size_t)(b * 64 + c)) * 4096);
    const v8u* gC = (const v8u*)((const unsigned short*)Cblob + ((size_t)(b * 64 + c)) * 4096);
    int r0 = tid >> 3, g0 = tid & 7;
#pragma unroll
    for (int it = 0; it < 2; it++) {
      int row = r0 + it * 32;
      *(v8u*)&sB[row][g0 * 8] = gB[row * 8 + g0];
      *(v8u*)&sC[row][g0 * 8] = gC[row * 8 + g0];
    }
  }
  if (wv == 0) {  // log-decay prefix scan
    float dtv = dtb[(size_t)(tok0 + lane) * HN + h];
    float lg = dlb[(size_t)(tok0 + lane) * HN + h];
#pragma unroll
    for (int d = 1; d < 64; d <<= 1) {
      float o = __shfl_up(lg, d);
      if (lane >= d) lg += o;
    }
    sla[lane] = lg;
    sdt[lane] = dtv;
    float la63 = __shfl(lg, 63);
    sdG[lane] = __expf(la63 - lg) * dtv;
    if (lane == 63) laq[blk] = __expf(la63);
  }
  __syncthreads();

  float Dh = Dp[h];
  {
    int s = lane;
    // conv+silu: wave wv owns p in [wv*16, wv*16+16) as 2 octets; 4x v8u reads
#pragma unroll
    for (int o = 0; o < 2; o++) {
      int p0 = (wv * 2 + o) * 8;
      v8u r0 = *(const v8u*)&sU.rawX[s + 0][p0];
      v8u r1 = *(const v8u*)&sU.rawX[s + 1][p0];
      v8u r2 = *(const v8u*)&sU.rawX[s + 2][p0];
      v8u r3 = *(const v8u*)&sU.rawX[s + 3][p0];
#pragma unroll
      for (int pp = 0; pp < 8; pp++) {
        int ch = h * 64 + p0 + pp;
        const float* w4 = conv_w + ch * 4;
        float acc = conv_b[ch] + us2f(r0[pp]) * w4[0] + us2f(r1[pp]) * w4[1] +
                    us2f(r2[pp]) * w4[2] + us2f(r3[pp]) * w4[3];
        sXT[p0 + pp][s] = f2us(acc / (1.f + __expf(-acc)));
      }
    }
#pragma unroll
    for (int it = 0; it < 16; it++) {
      int n = wv + it * 4;
      sBT[n][s] = f2us(us2f(sB[s][n]) * sdG[s]);
    }
  }
  __syncthreads();

  {  // W = C @ B^T, masked decay
    v4f acc[4];
#pragma unroll
    for (int j = 0; j < 4; j++) acc[j] = {0.f, 0.f, 0.f, 0.f};
    __builtin_amdgcn_s_setprio(1);
#pragma unroll
    for (int k0 = 0; k0 < 2; k0++) {
      v8s a = *(const v8s*)&sC[16 * wv + l15][k0 * 32 + quad * 8];
#pragma unroll
      for (int j = 0; j < 4; j++) {
        v8s bb = *(const v8s*)&sB[16 * j + l15][k0 * 32 + quad * 8];
        acc[j] = __builtin_amdgcn_mfma_f32_16x16x32_bf16(a, bb, acc[j], 0, 0, 0);
      }
    }
    __builtin_amdgcn_s_setprio(0);
    float lat[4];
#pragma unroll
    for (int r = 0; r < 4; r++) lat[r] = sla[16 * wv + quad * 4 + r];
#pragma unroll
    for (int j = 0; j < 4; j++) {
      int s = 16 * j + l15;
      float las = sla[s], dts = sdt[s];
#pragma unroll
      for (int r = 0; r < 4; r++) {
        int t = 16 * wv + quad * 4 + r;
        float w = (s <= t) ? __expf(lat[r] - las) * dts * acc[j][r] : 0.f;
        sU.W[t][s] = f2us(w);
      }
    }
  }
  __syncthreads();

  {  // y = W @ X + D*x; G = X @ BT
    v4f ya[4], ga[4];
#pragma unroll
    for (int j = 0; j < 4; j++) {
      ya[j] = {0.f, 0.f, 0.f, 0.f};
      ga[j] = {0.f, 0.f, 0.f, 0.f};
    }
    __builtin_amdgcn_s_setprio(1);
#pragma unroll
    for (int k0 = 0; k0 < 2; k0++) {
      v8s aw = *(const v8s*)&sU.W[16 * wv + l15][k0 * 32 + quad * 8];
      v8s ax = *(const v8s*)&sXT[16 * wv + l15][k0 * 32 + quad * 8];
#pragma unroll
      for (int j = 0; j < 4; j++) {
        v8s bx = *(const v8s*)&sXT[16 * j + l15][k0 * 32 + quad * 8];
        v8s bt = *(const v8s*)&sBT[16 * j + l15][k0 * 32 + quad * 8];
        ya[j] = __builtin_amdgcn_mfma_f32_16x16x32_bf16(aw, bx, ya[j], 0, 0, 0);
        ga[j] = __builtin_amdgcn_mfma_f32_16x16x32_bf16(ax, bt, ga[j], 0, 0, 0);
      }
    }
    __builtin_amdgcn_s_setprio(0);
#pragma unroll
    for (int j = 0; j < 4; j++) {
      int col = 16 * j + l15;
#pragma unroll
      for (int r = 0; r < 4; r++) {
        int row = 16 * wv + quad * 4 + r;
        float yv = ya[j][r] + Dh * us2f(sXT[col][row]);
        sB[row][col] = f2us(yv);
        sC[row][col] = f2us(ga[j][r]);
      }
    }
  }
  __syncthreads();

  {  // blob out: 2 passes of 16B
    v8u* gY = (v8u*)(Yblob + (size_t)blk * 4096);
    v8u* gG = (v8u*)(Gblob + (size_t)blk * 4096);
#pragma unroll
    for (int it = 0; it < 2; it++) {
      int i = tid + it * 256;
      int row = i >> 3, j = i & 7;
      gY[row * 8 + j] = *(const v8u*)&sB[row][j * 8];
      gG[row * 8 + j] = *(const v8u*)&sC[row][j * 8];
    }
  }
}

// ---------------- chunked SSD: inter-chunk state recurrence ----------------
// Round-8: 4 blocks per (b,h) so all 256 CUs participate (384 blocks total).
// Thread owns 4 states (8B); per chunk: 8B load (next G) + 8B store (prefix).
// Identical per-element math/order to the old 16-state version.
__global__ __launch_bounds__(256) void state_scan_kernel(
    bf16* __restrict__ blob, const float* __restrict__ laq) {
  int blk = blockIdx.x;
  int bh = blk >> 2, qq = blk & 3;
  int tid = threadIdx.x;
  size_t base = (size_t)bh * 64 * 4096 +
                (size_t)(qq * 16 + (tid >> 4)) * 64 + (size_t)(tid & 15) * 4;
  float S[4];
#pragma unroll
  for (int i = 0; i < 4; i++) S[i] = 0.f;
  for (int c = 0; c < 64; c++) {
    float q = laq[bh * 64 + c];
    unsigned short* gp = (unsigned short*)blob + base + (size_t)c * 4096;
    v4u ga = *(v4u*)gp;
    v4u pa;
#pragma unroll
    for (int i = 0; i < 4; i++) pa[i] = f2us(S[i]);
    *(v4u*)gp = pa;
#pragma unroll
    for (int i = 0; i < 4; i++) S[i] = q * S[i] + us2f(ga[i]);
  }
}

// ---------------- chunked SSD: inter-chunk y contribution (MFMA) ----------------
__global__ __launch_bounds__(256) void chunk_inter_kernel(
    const bf16* __restrict__ Cblob, const float* __restrict__ dlb,
    const bf16* __restrict__ blob, bf16* __restrict__ Yblob) {
  int blk = blockIdx.x;
  int c = blk & 63, bh = blk >> 6;
  int h = bh % HN, b = bh / HN;
  int tid = threadIdx.x, lane = tid & 63, wv = tid >> 6;
  int l15 = lane & 15, quad = lane >> 4;
  int tok0 = b * SEQL + c * 64;

  __shared__ unsigned short sC[64][LS];
  __shared__ unsigned short sY[64][LS];
  __shared__ float sel[64];

  {
    const v8u* gC = (const v8u*)((const unsigned short*)Cblob + ((size_t)(b * 64 + c)) * 4096);
    int r0 = tid >> 3, g0 = tid & 7;
#pragma unroll
    for (int it = 0; it < 2; it++) {
      int row = r0 + it * 32;
      *(v8u*)&sC[row][g0 * 8] = gC[row * 8 + g0];
    }
  }
  if (wv == 0) {
    float lg = dlb[(size_t)(tok0 + lane) * HN + h];
#pragma unroll
    for (int d = 1; d < 64; d <<= 1) {
      float o = __shfl_up(lg, d);
      if (lane >= d) lg += o;
    }
    sel[lane] = __expf(lg);
  }
  __syncthreads();
  {
    v4f acc[4];
#pragma unroll
    for (int j = 0; j < 4; j++) acc[j] = {0.f, 0.f, 0.f, 0.f};
    const unsigned short* gS = (const unsigned short*)blob + (size_t)blk * 4096;
    __builtin_amdgcn_s_setprio(1);
#pragma unroll
    for (int k0 = 0; k0 < 2; k0++) {
      v8s a = *(const v8s*)&sC[16 * wv + l15][k0 * 32 + quad * 8];
#pragma unroll
      for (int j = 0; j < 4; j++) {
        v8s bS = *(const v8s*)(gS + (size_t)(16 * j + l15) * 64 + k0 * 32 + quad * 8);
        acc[j] = __builtin_amdgcn_mfma_f32_16x16x32_bf16(a, bS, acc[j], 0, 0, 0);
      }
    }
    __builtin_amdgcn_s_setprio(0);
    float selt[4];
#pragma unroll
    for (int r = 0; r < 4; r++) selt[r] = sel[16 * wv + quad * 4 + r];
#pragma unroll
    for (int j = 0; j < 4; j++)
#pragma unroll
      for (int r = 0; r < 4; r++)
        sY[16 * wv + quad * 4 + r][16 * j + l15] = f2us(selt[r] * acc[j][r]);
  }
  __syncthreads();
  {  // Y RMW: 2 passes of 16B
    v8u* gY = (v8u*)(Yblob + (size_t)blk * 4096);
#pragma unroll
    for (int it = 0; it < 2; it++) {
      int i = tid + it * 256;
      int row = i >> 3, j = i & 7;
      v8u old = gY[row * 8 + j];
      v8u add = *(const v8u*)&sY[row][j * 8];
      v8u outv;
#pragma unroll
      for (int e = 0; e < 8; e++) outv[e] = f2us(us2f(old[e]) + us2f(add[e]));
      gY[row * 8 + j] = outv;
    }
  }
}

// ---------------- gated RMSNorm: blob y + z rows -> ynorm rows ----------------
// Paired (4B) loads/stores: 3 iterations of 2 channels.
__global__ __launch_bounds__(256) void norm_kernel(
    const bf16* __restrict__ Yblob, const bf16* __restrict__ z,
    const float* __restrict__ norm_w, bf16* __restrict__ out) {
  int token = blockIdx.x;
  int tid = threadIdx.x;
  int b = token >> 12, l = token & 4095, c = l >> 6, t = l & 63;
  const unsigned short* zp = (const unsigned short*)z + (size_t)token * DINNER;
  float vals[6];
  float ss = 0.f;
#pragma unroll
  for (int i = 0; i < 3; i++) {
    int q = tid + i * 256;          // pair index 0..767
    int ch = q * 2;
    int hh = ch >> 6, p = ch & 63;  // p even
    size_t yi = ((((size_t)(b * HN + hh)) * 64 + c) * 64 + t) * 64 + p;
    unsigned int yv2 = *(const unsigned int*)((const unsigned short*)Yblob + yi);
    unsigned int zv2 = *(const unsigned int*)(zp + ch);
#pragma unroll
    for (int e = 0; e < 2; e++) {
      float yv = us2f((unsigned short)((yv2 >> (16 * e)) & 0xffff));
      float zv = us2f((unsigned short)((zv2 >> (16 * e)) & 0xffff));
      float g = zv / (1.f + __expf(-zv));
      float v = yv * g;
      vals[i * 2 + e] = v;
      ss += v * v;
    }
  }
  for (int off = 32; off > 0; off >>= 1) ss += __shfl_down(ss, off);
  __shared__ float sred[4];
  if ((tid & 63) == 0) sred[tid >> 6] = ss;
  __syncthreads();
  float tot = sred[0] + sred[1] + sred[2] + sred[3];
  float scale = rsqrtf(tot / (float)DINNER + 1e-5f);
#pragma unroll
  for (int i = 0; i < 3; i++) {
    int q = tid + i * 256;
    int ch = q * 2;
    unsigned int o =
        (unsigned int)f2us(vals[i * 2] * scale * norm_w[ch]) |
        ((unsigned int)f2us(vals[i * 2 + 1] * scale * norm_w[ch + 1]) << 16);
    *(unsigned int*)((unsigned short*)out + (size_t)token * DINNER + ch) = o;
  }
}

// ---------------- launch ----------------
extern "C" void kernel_launch(void* const* d_in, const int* in_sizes, int n_in,
                              void* d_out, int out_size, void* d_ws, size_t ws_size,
                              hipStream_t stream) {
  const float* x = (const float*)d_in[0];
  const float* fus_w = (const float*)d_in[1];
  const float* fus_b = (const float*)d_in[2];
  const float* in_w[2] = {(const float*)d_in[3], (const float*)d_in[11]};
  const float* conv_w[2] = {(const float*)d_in[4], (const float*)d_in[12]};
  const float* conv_b[2] = {(const float*)d_in[5], (const float*)d_in[13]};
  const float* dt_bias[2] = {(const float*)d_in[6], (const float*)d_in[14]};
  const float* A_log[2] = {(const float*)d_in[7], (const float*)d_in[15]};
  const float* Dp[2] = {(const float*)d_in[8], (const float*)d_in[16]};
  const float* norm_w[2] = {(const float*)d_in[9], (const float*)d_in[17]};
  const float* out_w[2] = {(const float*)d_in[10], (const float*)d_in[18]};
  (void)in_sizes; (void)n_in;

  char* ws = (char*)d_ws;
  size_t off = 0;
  auto alloc = [&](size_t bytes) {
    size_t o = off;
    off = (off + bytes + 255) & ~(size_t)255;
    return o;
  };
  bf16* x_bf  = (bf16*)(ws + alloc((size_t)NTOK * DMODEL * 2));          // 25.2 MB
  bf16* w_in  = (bf16*)(ws + alloc((size_t)NROWS_XBC * DMODEL * 2));     //  4.9 MB
  bf16* wf1   = (bf16*)(ws + alloc((size_t)DMODEL * DMODEL * 2));        //  1.2 MB
  bf16* owT   = (bf16*)(ws + alloc((size_t)DINNER * DMODEL * 2));        //  2.4 MB
  bf16* wc    = (bf16*)(ws + alloc((size_t)DMODEL * DINNER * 2));        //  2.4 MB
  bf16* xbcr  = (bf16*)(ws + alloc((size_t)NTOK * CONVDIM * 2));         // 54.5 MB (ynorm aliases)
  float* dtb0 = (float*)(ws + alloc((size_t)NTOK * HN * 4));             //  1.6 MB
  float* dlb0 = (float*)(ws + alloc((size_t)NTOK * HN * 4));             //  1.6 MB
  float* dtb1 = (float*)(ws + alloc((size_t)NTOK * HN * 4));             //  1.6 MB
  float* dlb1 = (float*)(ws + alloc((size_t)NTOK * HN * 4));             //  1.6 MB
  float* laq  = (float*)(ws + alloc((size_t)BATCHN * HN * NCHUNK * 4));  //  0.02 MB
  bf16* Bblob = (bf16*)(ws + alloc((size_t)NTOK * DSTATE * 2));          //  2.1 MB
  bf16* Cblob = (bf16*)(ws + alloc((size_t)NTOK * DSTATE * 2));          //  2.1 MB
  bf16* Gblob = (bf16*)(ws + alloc((size_t)NTOK * DINNER * 2));          // 50.3 MB (z aliases)
  bf16* Yblob = (bf16*)(ws + alloc((size_t)NTOK * DINNER * 2));          // 50.3 MB
  bf16* zbuf  = Gblob;  // z GEMM output reuses G/prefix blob (dead after chunk_inter)
  bf16* ynorm = xbcr;   // normalized y reuses xbcr (dead after chunk_inter)
  float* dtbs[2] = {dtb0, dtb1};
  float* dlbs[2] = {dlb0, dlb1};

  if (ws_size < off) {  // diagnostic: clean absmax(=max|ref|) failure, not a crash
    hipMemsetAsync(d_out, 0, (size_t)out_size * 4, stream);
    return;
  }

  cast_x_kernel<<<(NTOK * DMODEL) / 1024, 256, 0, stream>>>(x, x_bf);
  // exact fp32 dt + log-decay, both directions in one x pass
  dt_fused_kernel<<<dim3(NTOK / 128, 2), 256, 0, stream>>>(
      x, in_w[0], in_w[1], dt_bias[0], dt_bias[1], A_log[0], A_log[1],
      dtb0, dlb0, dtb1, dlb1);

  for (int dir = 0; dir < 2; dir++) {
    cast_kernel<<<(NROWS_XBC * DMODEL) / 1024, 256, 0, stream>>>(in_w[dir], w_in);
    // in-proj xBC part (in_w rows 1536..3200) -> xbcr
    gemm_lds<true><<<dim3(NTOK / 128, CONVDIM / 128), 256, 0, stream>>>(
        x_bf, w_in + (size_t)DINNER * DMODEL, xbcr, DMODEL, CONVDIM, dir, 0, 0, nullptr);
    // B/C conv+silu once -> per-chunk blobs
    conv_bc_kernel<<<(NTOK * 16) / 256, 256, 0, stream>>>(
        xbcr, conv_w[dir], conv_b[dir], Bblob, Cblob);
    // chunked SSD
    chunk_intra_kernel<<<BATCHN * HN * NCHUNK, 256, 0, stream>>>(
        xbcr, Bblob, Cblob, conv_w[dir], conv_b[dir], dtbs[dir], dlbs[dir], Dp[dir],
        Yblob, Gblob, laq);
    state_scan_kernel<<<BATCHN * HN * 4, 256, 0, stream>>>(Gblob, laq);
    chunk_inter_kernel<<<BATCHN * HN * NCHUNK, 256, 0, stream>>>(Cblob, dlbs[dir], Gblob, Yblob);
    // in-proj z part (in_w rows 0..1536) -> zbuf (blob region, now dead)
    gemm_lds<true><<<dim3(NTOK / 128, DINNER / 128), 256, 0, stream>>>(
        x_bf, w_in, zbuf, DMODEL, DINNER, dir, 0, 0, nullptr);
    // gated RMSNorm -> ynorm rows (xbcr region, now dead)
    norm_kernel<<<NTOK, 256, 0, stream>>>(Yblob, zbuf, norm_w[dir], ynorm);
    // combined weight wc = fus_half @ out_w  (768x1536)
    cast_strided_kernel<<<(DMODEL * DMODEL) / 1024, 256, 0, stream>>>(
        fus_w + dir * DMODEL, wf1, DMODEL, 2 * DMODEL);
    transpose_ow_kernel<<<(DINNER * DMODEL) / 1024, 256, 0, stream>>>(out_w[dir], owT);
    gemm_lds<true><<<dim3(DMODEL / 128, DINNER / 128), 256, 0, stream>>>(
        wf1, owT, wc, DMODEL, DINNER, 0, 0, 0, nullptr);
    // out-proj + fusion: d_out (+)= ynorm @ wc^T (dir1 un-flips rows, accumulates)
    gemm_lds<false><<<dim3(NTOK / 128, DMODEL / 128), 256, 0, stream>>>(
        ynorm, wc, d_out, DINNER, DMODEL, 0, dir, dir, dir == 0 ? fus_b : nullptr);
  }
}

// Round 9
// 900.467 us; speedup vs baseline: 1.0448x; 1.0155x over previous
//
#include <hip/hip_runtime.h>
#include <hip/hip_bf16.h>

// BiMamba: bidirectional Mamba2 forward, MI355X/gfx950.
// Per direction: in-proj (bf16 MFMA GEMM, A-row flip for backward) -> exact
// fp32 dt/log-decay (fused both-dir tiled GEMV, also emits x_bf) -> conv+silu
// for B/C once into per-chunk blobs -> chunked SSD scan (three 64^3 matmuls on
// MFMA) -> z GEMM -> gated RMSNorm -> combined out-proj+fusion GEMM -> d_out.
// GEMM (round-5 form, measured best): 128x128 tile, BK=32, async global->LDS
// (16B), DOUBLE-buffered LDS with ONE barrier per k-step. Round-6 A/B showed
// counted-vmcnt 3-buf is null; round-4 showed XCD swizzle breaks the natural
// x-major L2 residency (xcd = blockIdx.x%8 -> per-XCD A set is 3.1 MB).
// Round-9: cast_x fused into dt_fused (x already in regs at staging; dir-0
// blocks emit x_bf, one 50MB-read dispatch removed); both dirs' wc GEMMs
// batched into one gridDim.z=2 launch (was 2x 72-block underutilized).
// Round-8: state_scan split 4x per (b,h) so all 256 CUs participate.
// Round-3: all scalar memory paths in the SSD chain vectorized to 16B (G13).

#define BATCHN 4
#define SEQL 4096
#define DMODEL 768
#define DINNER 1536
#define DSTATE 64
#define HN 24
#define CONVDIM 1664          // DINNER + 2*DSTATE
#define NROWS_XBC 3200        // DINNER + CONVDIM (in_w rows GEMMed; dt rows excluded)
#define NTOK (BATCHN*SEQL)    // 16384
#define NCHUNK 64             // SEQL / 64
#define LS 72                 // LDS stride (shorts) for chunk kernels
#define GBUF (128 * 32)       // one GEMM LDS buffer (shorts)

typedef short v8s __attribute__((ext_vector_type(8)));
typedef unsigned short v8u __attribute__((ext_vector_type(8)));
typedef unsigned short v4u __attribute__((ext_vector_type(4)));
typedef float v4f __attribute__((ext_vector_type(4)));
typedef unsigned int v2u32 __attribute__((ext_vector_type(2)));
typedef __hip_bfloat16 bf16;

__device__ __forceinline__ int flip_row(int r) {
  return (r & ~4095) | (4095 - (r & 4095));
}
__device__ __forceinline__ float us2f(unsigned short u) {
  return __uint_as_float(((unsigned int)u) << 16);
}
__device__ __forceinline__ unsigned short f2us(float f) {
  bf16 b = __float2bfloat16(f);
  return __builtin_bit_cast(unsigned short, b);
}
// async 16B/lane global->LDS; LDS dest = wave-uniform base + lane*16
__device__ __forceinline__ void async16(const unsigned short* g, unsigned short* l) {
  __builtin_amdgcn_global_load_lds(
      (const __attribute__((address_space(1))) unsigned int*)(const void*)g,
      (__attribute__((address_space(3))) unsigned int*)(void*)l, 16, 0, 0);
}

// ---------------- cast kernels (4-wide) ----------------

__global__ void cast_kernel(const float* __restrict__ src, bf16* __restrict__ dst) {
  int idx = blockIdx.x * 256 + threadIdx.x;   // x4 elements
  v4f v = *(const v4f*)(src + (size_t)idx * 4);
  v2u32 o;
  o[0] = (unsigned int)f2us(v[0]) | ((unsigned int)f2us(v[1]) << 16);
  o[1] = (unsigned int)f2us(v[2]) | ((unsigned int)f2us(v[3]) << 16);
  *(v2u32*)((unsigned short*)dst + (size_t)idx * 4) = o;
}

// dst[j*cols+m] = src[j*src_stride+m]  (extract fus_w half), 4-wide (cols%4==0)
__global__ void cast_strided_kernel(const float* __restrict__ src, bf16* __restrict__ dst,
                                    int cols, int src_stride) {
  int idx4 = (blockIdx.x * 256 + threadIdx.x) * 4;
  int j = idx4 / cols, m = idx4 % cols;
  v4f v = *(const v4f*)(src + (size_t)j * src_stride + m);
  v2u32 o;
  o[0] = (unsigned int)f2us(v[0]) | ((unsigned int)f2us(v[1]) << 16);
  o[1] = (unsigned int)f2us(v[2]) | ((unsigned int)f2us(v[3]) << 16);
  *(v2u32*)((unsigned short*)dst + idx4) = o;
}

// dst[k*768+c] = src[c*1536+k] (out_w -> owT); 4 strided reads, 8B write
__global__ void transpose_ow_kernel(const float* __restrict__ src, bf16* __restrict__ dst) {
  int idx4 = (blockIdx.x * 256 + threadIdx.x) * 4;
  int k = idx4 / DMODEL, c0 = idx4 % DMODEL;
  unsigned short u[4];
#pragma unroll
  for (int i = 0; i < 4; i++)
    u[i] = f2us(src[(size_t)(c0 + i) * DINNER + k]);
  v2u32 o;
  o[0] = (unsigned int)u[0] | ((unsigned int)u[1] << 16);
  o[1] = (unsigned int)u[2] | ((unsigned int)u[3] << 16);
  *(v2u32*)((unsigned short*)dst + idx4) = o;
}

// ------- bf16 MFMA GEMM, LDS-staged, double-buffered: C[M,N]=A[M,K]@B[N,K]^T -------
// 128x128 tile, BK=32. Per k-step: issue next tile's 4 async16 into buf^1,
// ds_read+MFMA from buf, ONE __syncthreads (its vmcnt/lgkm drain covers the
// staged loads AFTER compute hid their latency). Natural block order (no
// swizzle) keeps per-XCD A working set L2-resident.
// zsA/zsB/zsC: per-blockIdx.z element strides (0 for normal 2D launches).
// flip_a: per-lane global row reversal (free). Epilogue: bias/flip_c/accum.
template <bool OUT_BF16>
__global__ __launch_bounds__(256) void gemm_lds(
    const bf16* __restrict__ A, const bf16* __restrict__ B, void* __restrict__ C,
    int K, int ldc, int flip_a, int flip_c, int accum,
    size_t zsA, size_t zsB, size_t zsC, const float* __restrict__ bias) {
  __shared__ unsigned short sA[2 * GBUF];
  __shared__ unsigned short sB[2 * GBUF];
  int tid = threadIdx.x;
  int wave = tid >> 6, lane = tid & 63;
  int l15 = lane & 15, quad = lane >> 4;
  int m0 = blockIdx.x * 128, n0 = blockIdx.y * 128;
  int mw = (wave >> 1) * 64, nw = (wave & 1) * 64;
  int zb = blockIdx.z;

  // staging addresses: wave w owns rows [w*32, w*32+32) of each tile
  int srow = wave * 32 + (lane >> 2);
  int scol = (lane & 3) * 8;
  const unsigned short* Ap = (const unsigned short*)A + (size_t)zb * zsA;
  const unsigned short* Bp = (const unsigned short*)B + (size_t)zb * zsB;
  void* Cz = OUT_BF16 ? (void*)((bf16*)C + (size_t)zb * zsC)
                      : (void*)((float*)C + (size_t)zb * zsC);
  int ar0 = m0 + srow, ar1 = m0 + srow + 16;
  if (flip_a) { ar0 = flip_row(ar0); ar1 = flip_row(ar1); }
  const unsigned short* ga0 = Ap + (size_t)ar0 * K + scol;
  const unsigned short* ga1 = Ap + (size_t)ar1 * K + scol;
  const unsigned short* gb0 = Bp + (size_t)(n0 + srow) * K + scol;
  const unsigned short* gb1 = Bp + (size_t)(n0 + srow + 16) * K + scol;
  int lo0 = (wave * 32) * 32;          // wave-uniform LDS offsets (shorts)
  int lo1 = (wave * 32 + 16) * 32;

  v4f acc[4][4];
#pragma unroll
  for (int i = 0; i < 4; i++)
#pragma unroll
    for (int j = 0; j < 4; j++) acc[i][j] = {0.f, 0.f, 0.f, 0.f};

  // prologue: stage k-step 0 into buffer 0
  async16(ga0, &sA[lo0]);
  async16(ga1, &sA[lo1]);
  async16(gb0, &sB[lo0]);
  async16(gb1, &sB[lo1]);
  __syncthreads();

  int nt = K >> 5;
  for (int t = 0; t < nt; t++) {
    int cur = (t & 1) * GBUF;
    if (t + 1 < nt) {           // issue next tile into the other buffer
      int k0 = (t + 1) << 5;
      int nx = ((t + 1) & 1) * GBUF;
      async16(ga0 + k0, &sA[nx + lo0]);
      async16(ga1 + k0, &sA[nx + lo1]);
      async16(gb0 + k0, &sB[nx + lo0]);
      async16(gb1 + k0, &sB[nx + lo1]);
    }
    v8s af[4], bfr[4];
#pragma unroll
    for (int i = 0; i < 4; i++)
      af[i] = *(const v8s*)&sA[cur + (mw + i * 16 + l15) * 32 + quad * 8];
#pragma unroll
    for (int j = 0; j < 4; j++)
      bfr[j] = *(const v8s*)&sB[cur + (nw + j * 16 + l15) * 32 + quad * 8];
#pragma unroll
    for (int i = 0; i < 4; i++)
#pragma unroll
      for (int j = 0; j < 4; j++)
        acc[i][j] = __builtin_amdgcn_mfma_f32_16x16x32_bf16(af[i], bfr[j], acc[i][j], 0, 0, 0);
    __syncthreads();  // drains vmcnt (next tile staged) + protects buf reuse
  }

  float bv[4];
#pragma unroll
  for (int j = 0; j < 4; j++) bv[j] = bias ? bias[n0 + nw + j * 16 + l15] : 0.f;

#pragma unroll
  for (int i = 0; i < 4; i++) {
#pragma unroll
    for (int r2 = 0; r2 < 4; r2++) {
      int row = m0 + mw + i * 16 + quad * 4 + r2;
      int orow = flip_c ? flip_row(row) : row;
#pragma unroll
      for (int j = 0; j < 4; j++) {
        int col = n0 + nw + j * 16 + l15;
        float v = acc[i][j][r2] + bv[j];
        size_t off = (size_t)orow * ldc + col;
        if (OUT_BF16) {
          ((bf16*)Cz)[off] = __float2bfloat16(v);
        } else {
          float* Cf = (float*)Cz;
          if (accum) v += Cf[off];
          Cf[off] = v;
        }
      }
    }
  }
}

// ---------------- fused fp32 dt path (both directions, one x pass) ----------------
// C[16384,48] = x[16384,768] @ W[48,768]^T, W = dt rows of in_w (fwd|bwd).
// Grid (128,2): blockIdx.y = dir. Block: 128 tokens x 24 cols, 256 threads;
// thread = (tok2 = lane, cg = 6-col group) owns tokens {base+tok2, base+64+tok2}
// so each sW read feeds 8 FMAs. acc[2][6] only -> no spill. Single-buffered LDS,
// direct global->LDS staging, unroll pinned (kc: 1, k4: 2) so the scheduler
// cannot hoist a chunk's worth of loads into registers (the round-1 spill).
// Round-9: dir-0 blocks also emit x_bf (bit-identical to the old cast_x) from
// the staged registers -- removes a separate 50MB-read dispatch.
__global__ __launch_bounds__(256) void dt_fused_kernel(
    const float* __restrict__ x, bf16* __restrict__ xbf,
    const float* __restrict__ in_w0, const float* __restrict__ in_w1,
    const float* __restrict__ dt_bias0, const float* __restrict__ dt_bias1,
    const float* __restrict__ A_log0, const float* __restrict__ A_log1,
    float* __restrict__ dt0, float* __restrict__ dl0,
    float* __restrict__ dt1, float* __restrict__ dl1) {
  __shared__ float sXT[64][128];  // [k][token] transposed
  __shared__ float sW[24][64];    // [col][k]
  int tid = threadIdx.x;
  int tok2 = tid & 63, cg = tid >> 6;   // cg owns cols [cg*6, cg*6+6)
  int dir = blockIdx.y;
  int tok_base = blockIdx.x * 128;

  // staging: 2 threads per token, 32 consecutive k-floats each (8x v4f)
  int st_tok = tid >> 1, st_k0 = (tid & 1) * 32;
  const float* xg = x + (size_t)(tok_base + st_tok) * DMODEL + st_k0;
  unsigned short* xbo =
      (unsigned short*)xbf + (size_t)(tok_base + st_tok) * DMODEL + st_k0;
  const float* wb = dir ? in_w1 : in_w0;
  const float* wrow = wb + (size_t)NROWS_XBC * DMODEL;

  float acc0[6], acc1[6];
#pragma unroll
  for (int c = 0; c < 6; c++) { acc0[c] = 0.f; acc1[c] = 0.f; }

#pragma unroll 1
  for (int kc = 0; kc < 12; kc++) {   // 768 / 64
#pragma unroll
    for (int i = 0; i < 8; i++) {
      v4f v = *(const v4f*)(xg + kc * 64 + i * 4);
#pragma unroll
      for (int j = 0; j < 4; j++) sXT[st_k0 + i * 4 + j][st_tok] = v[j];
      if (dir == 0) {   // emit x_bf (identical values to old cast_x_kernel)
        v2u32 o;
        o[0] = (unsigned int)f2us(v[0]) | ((unsigned int)f2us(v[1]) << 16);
        o[1] = (unsigned int)f2us(v[2]) | ((unsigned int)f2us(v[3]) << 16);
        *(v2u32*)(xbo + kc * 64 + i * 4) = o;
      }
    }
    for (int i = tid; i < 24 * 16; i += 256) {
      int col = i >> 4, k4 = i & 15;
      *(v4f*)&sW[col][k4 * 4] =
          *(const v4f*)(wrow + (size_t)col * DMODEL + kc * 64 + k4 * 4);
    }
    __syncthreads();
#pragma unroll 2
    for (int k4 = 0; k4 < 16; k4++) {
      float xa[4], xb[4];
#pragma unroll
      for (int j = 0; j < 4; j++) {
        xa[j] = sXT[k4 * 4 + j][tok2];
        xb[j] = sXT[k4 * 4 + j][tok2 + 64];
      }
#pragma unroll
      for (int c = 0; c < 6; c++) {
        v4f wv = *(const v4f*)&sW[cg * 6 + c][k4 * 4];
#pragma unroll
        for (int j = 0; j < 4; j++) {
          acc0[c] = fmaf(xa[j], wv[j], acc0[c]);
          acc1[c] = fmaf(xb[j], wv[j], acc1[c]);
        }
      }
    }
    __syncthreads();
  }

  // epilogue: exact fp32 softplus / decay (identical formulas to old dt_kernel)
  const float* dtB = dir ? dt_bias1 : dt_bias0;
  const float* Alg = dir ? A_log1 : A_log0;
  float* dto = dir ? dt1 : dt0;
  float* dlo = dir ? dl1 : dl0;
#pragma unroll
  for (int t = 0; t < 2; t++) {
    int r = tok_base + t * 64 + tok2;
    size_t row = dir ? (size_t)flip_row(r) : (size_t)r;
#pragma unroll
    for (int c = 0; c < 6; c++) {
      int h = cg * 6 + c;
      float v = (t ? acc1[c] : acc0[c]) + dtB[h];
      float dtv = (v > 20.f) ? v : log1pf(expf(v));
      dto[row * HN + h] = dtv;
      dlo[row * HN + h] = -dtv * expf(Alg[h]);
    }
  }
}

// ---------------- conv+silu for B/C channels -> per-chunk blobs ----------------
// Thread = (token, 8-channel octet): 4x v8u taps, 8 outputs, one 16B store.
__global__ void conv_bc_kernel(const bf16* __restrict__ xbcr,
                               const float* __restrict__ conv_w,
                               const float* __restrict__ conv_b,
                               bf16* __restrict__ Bblob, bf16* __restrict__ Cblob) {
  int idx = blockIdx.x * 256 + threadIdx.x;  // NTOK*16
  int token = idx >> 4, oct = idx & 15;
  int b = token >> 12, l = token & 4095, c = l >> 6, s = l & 63;
  int ch0 = 1536 + oct * 8;
  const unsigned short* xp = (const unsigned short*)xbcr;
  v8u tv[4];
#pragma unroll
  for (int j = 0; j < 4; j++) {
    int ls = l - 3 + j;
    v8u z = {0, 0, 0, 0, 0, 0, 0, 0};
    tv[j] = z;
    if (ls >= 0)
      tv[j] = *(const v8u*)(xp + (size_t)((b << 12) | ls) * CONVDIM + ch0);
  }
  v8u ov;
#pragma unroll
  for (int e = 0; e < 8; e++) {
    int ch = ch0 + e;
    const float* w4 = conv_w + ch * 4;
    float acc = conv_b[ch];
#pragma unroll
    for (int j = 0; j < 4; j++) acc += us2f(tv[j][e]) * w4[j];
    ov[e] = f2us(acc / (1.f + __expf(-acc)));
  }
  size_t base = ((size_t)((b * 64 + c) * 64 + s)) * 64;
  int ch7 = oct * 8;
  if (ch7 < 64) *(v8u*)((unsigned short*)Bblob + base + ch7) = ov;
  else          *(v8u*)((unsigned short*)Cblob + base + ch7 - 64) = ov;
}

// ---------------- chunked SSD: intra-chunk kernel (MFMA) ----------------
__global__ __launch_bounds__(256) void chunk_intra_kernel(
    const bf16* __restrict__ xbcr, const bf16* __restrict__ Bblob,
    const bf16* __restrict__ Cblob, const float* __restrict__ conv_w,
    const float* __restrict__ conv_b, const float* __restrict__ dtb,
    const float* __restrict__ dlb, const float* __restrict__ Dp,
    bf16* __restrict__ Yblob, bf16* __restrict__ Gblob, float* __restrict__ laq) {
  int blk = blockIdx.x;
  int c = blk & 63, bh = blk >> 6;
  int h = bh % HN, b = bh / HN;
  int tid = threadIdx.x, lane = tid & 63, wv = tid >> 6;
  int l15 = lane & 15, quad = lane >> 4;
  int tok0 = b * SEQL + c * 64;

  __shared__ unsigned short sXT[64][LS];  // [p][s]
  __shared__ unsigned short sB [64][LS];  // [s][n]; later sY [t][p]
  __shared__ unsigned short sBT[64][LS];  // [n][s] dG-scaled
  __shared__ unsigned short sC [64][LS];  // [t][n]; later sG [p][n]
  // rawX stride 72 shorts (144B): v8u rows 16B-aligned; dead before W written
  __shared__ union { unsigned short rawX[67][72]; unsigned short W[64][LS]; } sU;
  __shared__ float sla[64], sdt[64], sdG[64];

  // rawX staging: 67 rows x 8 v8u = 536 16B units (coalesced: 8 thr/row)
  for (int i = tid; i < 536; i += 256) {
    int r = i >> 3, j = i & 7;
    int l = c * 64 + r - 3;
    v8u v = {0, 0, 0, 0, 0, 0, 0, 0};
    if (l >= 0)
      v = *(const v8u*)((const unsigned short*)xbcr +
                        (size_t)(b * SEQL + l) * CONVDIM + h * 64 + j * 8);
    *(v8u*)&sU.rawX[r][j * 8] = v;
  }
  {
    const v8u* gB = (const v8u*)((const unsigned short*)Bblob + ((size_t)(b * 64 + c)) * 4096);
    const v8u* gC = (const v8u*)((const unsigned short*)Cblob + ((size_t)(b * 64 + c)) * 4096);
    int r0 = tid >> 3, g0 = tid & 7;
#pragma unroll
    for (int it = 0; it < 2; it++) {
      int row = r0 + it * 32;
      *(v8u*)&sB[row][g0 * 8] = gB[row * 8 + g0];
      *(v8u*)&sC[row][g0 * 8] = gC[row * 8 + g0];
    }
  }
  if (wv == 0) {  // log-decay prefix scan
    float dtv = dtb[(size_t)(tok0 + lane) * HN + h];
    float lg = dlb[(size_t)(tok0 + lane) * HN + h];
#pragma unroll
    for (int d = 1; d < 64; d <<= 1) {
      float o = __shfl_up(lg, d);
      if (lane >= d) lg += o;
    }
    sla[lane] = lg;
    sdt[lane] = dtv;
    float la63 = __shfl(lg, 63);
    sdG[lane] = __expf(la63 - lg) * dtv;
    if (lane == 63) laq[blk] = __expf(la63);
  }
  __syncthreads();

  float Dh = Dp[h];
  {
    int s = lane;
    // conv+silu: wave wv owns p in [wv*16, wv*16+16) as 2 octets; 4x v8u reads
#pragma unroll
    for (int o = 0; o < 2; o++) {
      int p0 = (wv * 2 + o) * 8;
      v8u r0 = *(const v8u*)&sU.rawX[s + 0][p0];
      v8u r1 = *(const v8u*)&sU.rawX[s + 1][p0];
      v8u r2 = *(const v8u*)&sU.rawX[s + 2][p0];
      v8u r3 = *(const v8u*)&sU.rawX[s + 3][p0];
#pragma unroll
      for (int pp = 0; pp < 8; pp++) {
        int ch = h * 64 + p0 + pp;
        const float* w4 = conv_w + ch * 4;
        float acc = conv_b[ch] + us2f(r0[pp]) * w4[0] + us2f(r1[pp]) * w4[1] +
                    us2f(r2[pp]) * w4[2] + us2f(r3[pp]) * w4[3];
        sXT[p0 + pp][s] = f2us(acc / (1.f + __expf(-acc)));
      }
    }
#pragma unroll
    for (int it = 0; it < 16; it++) {
      int n = wv + it * 4;
      sBT[n][s] = f2us(us2f(sB[s][n]) * sdG[s]);
    }
  }
  __syncthreads();

  {  // W = C @ B^T, masked decay
    v4f acc[4];
#pragma unroll
    for (int j = 0; j < 4; j++) acc[j] = {0.f, 0.f, 0.f, 0.f};
    __builtin_amdgcn_s_setprio(1);
#pragma unroll
    for (int k0 = 0; k0 < 2; k0++) {
      v8s a = *(const v8s*)&sC[16 * wv + l15][k0 * 32 + quad * 8];
#pragma unroll
      for (int j = 0; j < 4; j++) {
        v8s bb = *(const v8s*)&sB[16 * j + l15][k0 * 32 + quad * 8];
        acc[j] = __builtin_amdgcn_mfma_f32_16x16x32_bf16(a, bb, acc[j], 0, 0, 0);
      }
    }
    __builtin_amdgcn_s_setprio(0);
    float lat[4];
#pragma unroll
    for (int r = 0; r < 4; r++) lat[r] = sla[16 * wv + quad * 4 + r];
#pragma unroll
    for (int j = 0; j < 4; j++) {
      int s = 16 * j + l15;
      float las = sla[s], dts = sdt[s];
#pragma unroll
      for (int r = 0; r < 4; r++) {
        int t = 16 * wv + quad * 4 + r;
        float w = (s <= t) ? __expf(lat[r] - las) * dts * acc[j][r] : 0.f;
        sU.W[t][s] = f2us(w);
      }
    }
  }
  __syncthreads();

  {  // y = W @ X + D*x; G = X @ BT
    v4f ya[4], ga[4];
#pragma unroll
    for (int j = 0; j < 4; j++) {
      ya[j] = {0.f, 0.f, 0.f, 0.f};
      ga[j] = {0.f, 0.f, 0.f, 0.f};
    }
    __builtin_amdgcn_s_setprio(1);
#pragma unroll
    for (int k0 = 0; k0 < 2; k0++) {
      v8s aw = *(const v8s*)&sU.W[16 * wv + l15][k0 * 32 + quad * 8];
      v8s ax = *(const v8s*)&sXT[16 * wv + l15][k0 * 32 + quad * 8];
#pragma unroll
      for (int j = 0; j < 4; j++) {
        v8s bx = *(const v8s*)&sXT[16 * j + l15][k0 * 32 + quad * 8];
        v8s bt = *(const v8s*)&sBT[16 * j + l15][k0 * 32 + quad * 8];
        ya[j] = __builtin_amdgcn_mfma_f32_16x16x32_bf16(aw, bx, ya[j], 0, 0, 0);
        ga[j] = __builtin_amdgcn_mfma_f32_16x16x32_bf16(ax, bt, ga[j], 0, 0, 0);
      }
    }
    __builtin_amdgcn_s_setprio(0);
#pragma unroll
    for (int j = 0; j < 4; j++) {
      int col = 16 * j + l15;
#pragma unroll
      for (int r = 0; r < 4; r++) {
        int row = 16 * wv + quad * 4 + r;
        float yv = ya[j][r] + Dh * us2f(sXT[col][row]);
        sB[row][col] = f2us(yv);
        sC[row][col] = f2us(ga[j][r]);
      }
    }
  }
  __syncthreads();

  {  // blob out: 2 passes of 16B
    v8u* gY = (v8u*)(Yblob + (size_t)blk * 4096);
    v8u* gG = (v8u*)(Gblob + (size_t)blk * 4096);
#pragma unroll
    for (int it = 0; it < 2; it++) {
      int i = tid + it * 256;
      int row = i >> 3, j = i & 7;
      gY[row * 8 + j] = *(const v8u*)&sB[row][j * 8];
      gG[row * 8 + j] = *(const v8u*)&sC[row][j * 8];
    }
  }
}

// ---------------- chunked SSD: inter-chunk state recurrence ----------------
// 4 blocks per (b,h) so all 256 CUs participate (384 blocks total).
__global__ __launch_bounds__(256) void state_scan_kernel(
    bf16* __restrict__ blob, const float* __restrict__ laq) {
  int blk = blockIdx.x;
  int bh = blk >> 2, qq = blk & 3;
  int tid = threadIdx.x;
  size_t base = (size_t)bh * 64 * 4096 +
                (size_t)(qq * 16 + (tid >> 4)) * 64 + (size_t)(tid & 15) * 4;
  float S[4];
#pragma unroll
  for (int i = 0; i < 4; i++) S[i] = 0.f;
  for (int c = 0; c < 64; c++) {
    float q = laq[bh * 64 + c];
    unsigned short* gp = (unsigned short*)blob + base + (size_t)c * 4096;
    v4u ga = *(v4u*)gp;
    v4u pa;
#pragma unroll
    for (int i = 0; i < 4; i++) pa[i] = f2us(S[i]);
    *(v4u*)gp = pa;
#pragma unroll
    for (int i = 0; i < 4; i++) S[i] = q * S[i] + us2f(ga[i]);
  }
}

// ---------------- chunked SSD: inter-chunk y contribution (MFMA) ----------------
__global__ __launch_bounds__(256) void chunk_inter_kernel(
    const bf16* __restrict__ Cblob, const float* __restrict__ dlb,
    const bf16* __restrict__ blob, bf16* __restrict__ Yblob) {
  int blk = blockIdx.x;
  int c = blk & 63, bh = blk >> 6;
  int h = bh % HN, b = bh / HN;
  int tid = threadIdx.x, lane = tid & 63, wv = tid >> 6;
  int l15 = lane & 15, quad = lane >> 4;
  int tok0 = b * SEQL + c * 64;

  __shared__ unsigned short sC[64][LS];
  __shared__ unsigned short sY[64][LS];
  __shared__ float sel[64];

  {
    const v8u* gC = (const v8u*)((const unsigned short*)Cblob + ((size_t)(b * 64 + c)) * 4096);
    int r0 = tid >> 3, g0 = tid & 7;
#pragma unroll
    for (int it = 0; it < 2; it++) {
      int row = r0 + it * 32;
      *(v8u*)&sC[row][g0 * 8] = gC[row * 8 + g0];
    }
  }
  if (wv == 0) {
    float lg = dlb[(size_t)(tok0 + lane) * HN + h];
#pragma unroll
    for (int d = 1; d < 64; d <<= 1) {
      float o = __shfl_up(lg, d);
      if (lane >= d) lg += o;
    }
    sel[lane] = __expf(lg);
  }
  __syncthreads();
  {
    v4f acc[4];
#pragma unroll
    for (int j = 0; j < 4; j++) acc[j] = {0.f, 0.f, 0.f, 0.f};
    const unsigned short* gS = (const unsigned short*)blob + (size_t)blk * 4096;
    __builtin_amdgcn_s_setprio(1);
#pragma unroll
    for (int k0 = 0; k0 < 2; k0++) {
      v8s a = *(const v8s*)&sC[16 * wv + l15][k0 * 32 + quad * 8];
#pragma unroll
      for (int j = 0; j < 4; j++) {
        v8s bS = *(const v8s*)(gS + (size_t)(16 * j + l15) * 64 + k0 * 32 + quad * 8);
        acc[j] = __builtin_amdgcn_mfma_f32_16x16x32_bf16(a, bS, acc[j], 0, 0, 0);
      }
    }
    __builtin_amdgcn_s_setprio(0);
    float selt[4];
#pragma unroll
    for (int r = 0; r < 4; r++) selt[r] = sel[16 * wv + quad * 4 + r];
#pragma unroll
    for (int j = 0; j < 4; j++)
#pragma unroll
      for (int r = 0; r < 4; r++)
        sY[16 * wv + quad * 4 + r][16 * j + l15] = f2us(selt[r] * acc[j][r]);
  }
  __syncthreads();
  {  // Y RMW: 2 passes of 16B
    v8u* gY = (v8u*)(Yblob + (size_t)blk * 4096);
#pragma unroll
    for (int it = 0; it < 2; it++) {
      int i = tid + it * 256;
      int row = i >> 3, j = i & 7;
      v8u old = gY[row * 8 + j];
      v8u add = *(const v8u*)&sY[row][j * 8];
      v8u outv;
#pragma unroll
      for (int e = 0; e < 8; e++) outv[e] = f2us(us2f(old[e]) + us2f(add[e]));
      gY[row * 8 + j] = outv;
    }
  }
}

// ---------------- gated RMSNorm: blob y + z rows -> ynorm rows ----------------
// Paired (4B) loads/stores: 3 iterations of 2 channels.
__global__ __launch_bounds__(256) void norm_kernel(
    const bf16* __restrict__ Yblob, const bf16* __restrict__ z,
    const float* __restrict__ norm_w, bf16* __restrict__ out) {
  int token = blockIdx.x;
  int tid = threadIdx.x;
  int b = token >> 12, l = token & 4095, c = l >> 6, t = l & 63;
  const unsigned short* zp = (const unsigned short*)z + (size_t)token * DINNER;
  float vals[6];
  float ss = 0.f;
#pragma unroll
  for (int i = 0; i < 3; i++) {
    int q = tid + i * 256;          // pair index 0..767
    int ch = q * 2;
    int hh = ch >> 6, p = ch & 63;  // p even
    size_t yi = ((((size_t)(b * HN + hh)) * 64 + c) * 64 + t) * 64 + p;
    unsigned int yv2 = *(const unsigned int*)((const unsigned short*)Yblob + yi);
    unsigned int zv2 = *(const unsigned int*)(zp + ch);
#pragma unroll
    for (int e = 0; e < 2; e++) {
      float yv = us2f((unsigned short)((yv2 >> (16 * e)) & 0xffff));
      float zv = us2f((unsigned short)((zv2 >> (16 * e)) & 0xffff));
      float g = zv / (1.f + __expf(-zv));
      float v = yv * g;
      vals[i * 2 + e] = v;
      ss += v * v;
    }
  }
  for (int off = 32; off > 0; off >>= 1) ss += __shfl_down(ss, off);
  __shared__ float sred[4];
  if ((tid & 63) == 0) sred[tid >> 6] = ss;
  __syncthreads();
  float tot = sred[0] + sred[1] + sred[2] + sred[3];
  float scale = rsqrtf(tot / (float)DINNER + 1e-5f);
#pragma unroll
  for (int i = 0; i < 3; i++) {
    int q = tid + i * 256;
    int ch = q * 2;
    unsigned int o =
        (unsigned int)f2us(vals[i * 2] * scale * norm_w[ch]) |
        ((unsigned int)f2us(vals[i * 2 + 1] * scale * norm_w[ch + 1]) << 16);
    *(unsigned int*)((unsigned short*)out + (size_t)token * DINNER + ch) = o;
  }
}

// ---------------- launch ----------------
extern "C" void kernel_launch(void* const* d_in, const int* in_sizes, int n_in,
                              void* d_out, int out_size, void* d_ws, size_t ws_size,
                              hipStream_t stream) {
  const float* x = (const float*)d_in[0];
  const float* fus_w = (const float*)d_in[1];
  const float* fus_b = (const float*)d_in[2];
  const float* in_w[2] = {(const float*)d_in[3], (const float*)d_in[11]};
  const float* conv_w[2] = {(const float*)d_in[4], (const float*)d_in[12]};
  const float* conv_b[2] = {(const float*)d_in[5], (const float*)d_in[13]};
  const float* dt_bias[2] = {(const float*)d_in[6], (const float*)d_in[14]};
  const float* A_log[2] = {(const float*)d_in[7], (const float*)d_in[15]};
  const float* Dp[2] = {(const float*)d_in[8], (const float*)d_in[16]};
  const float* norm_w[2] = {(const float*)d_in[9], (const float*)d_in[17]};
  const float* out_w[2] = {(const float*)d_in[10], (const float*)d_in[18]};
  (void)in_sizes; (void)n_in;

  char* ws = (char*)d_ws;
  size_t off = 0;
  auto alloc = [&](size_t bytes) {
    size_t o = off;
    off = (off + bytes + 255) & ~(size_t)255;
    return o;
  };
  bf16* x_bf  = (bf16*)(ws + alloc((size_t)NTOK * DMODEL * 2));              // 25.2 MB
  bf16* w_in  = (bf16*)(ws + alloc((size_t)NROWS_XBC * DMODEL * 2));         //  4.9 MB
  bf16* wf1   = (bf16*)(ws + alloc((size_t)2 * DMODEL * DMODEL * 2));        //  2.4 MB (x2 dirs)
  bf16* owT   = (bf16*)(ws + alloc((size_t)2 * DINNER * DMODEL * 2));        //  4.7 MB (x2 dirs)
  bf16* wc    = (bf16*)(ws + alloc((size_t)2 * DMODEL * DINNER * 2));        //  4.7 MB (x2 dirs)
  bf16* xbcr  = (bf16*)(ws + alloc((size_t)NTOK * CONVDIM * 2));             // 54.5 MB (ynorm aliases)
  float* dtb0 = (float*)(ws + alloc((size_t)NTOK * HN * 4));                 //  1.6 MB
  float* dlb0 = (float*)(ws + alloc((size_t)NTOK * HN * 4));                 //  1.6 MB
  float* dtb1 = (float*)(ws + alloc((size_t)NTOK * HN * 4));                 //  1.6 MB
  float* dlb1 = (float*)(ws + alloc((size_t)NTOK * HN * 4));                 //  1.6 MB
  float* laq  = (float*)(ws + alloc((size_t)BATCHN * HN * NCHUNK * 4));      //  0.02 MB
  bf16* Bblob = (bf16*)(ws + alloc((size_t)NTOK * DSTATE * 2));              //  2.1 MB
  bf16* Cblob = (bf16*)(ws + alloc((size_t)NTOK * DSTATE * 2));              //  2.1 MB
  bf16* Gblob = (bf16*)(ws + alloc((size_t)NTOK * DINNER * 2));              // 50.3 MB (z aliases)
  bf16* Yblob = (bf16*)(ws + alloc((size_t)NTOK * DINNER * 2));              // 50.3 MB
  bf16* zbuf  = Gblob;  // z GEMM output reuses G/prefix blob (dead after chunk_inter)
  bf16* ynorm = xbcr;   // normalized y reuses xbcr (dead after chunk_inter)
  float* dtbs[2] = {dtb0, dtb1};
  float* dlbs[2] = {dlb0, dlb1};

  if (ws_size < off) {  // diagnostic: clean absmax(=max|ref|) failure, not a crash
    hipMemsetAsync(d_out, 0, (size_t)out_size * 4, stream);
    return;
  }

  // exact fp32 dt + log-decay, both directions in one x pass; also emits x_bf
  dt_fused_kernel<<<dim3(NTOK / 128, 2), 256, 0, stream>>>(
      x, x_bf, in_w[0], in_w[1], dt_bias[0], dt_bias[1], A_log[0], A_log[1],
      dtb0, dlb0, dtb1, dlb1);

  // combined weights wc_d = fus_half_d @ out_w_d (768x1536), both dirs batched
  for (int d = 0; d < 2; d++) {
    cast_strided_kernel<<<(DMODEL * DMODEL) / 1024, 256, 0, stream>>>(
        fus_w + d * DMODEL, wf1 + (size_t)d * DMODEL * DMODEL, DMODEL, 2 * DMODEL);
    transpose_ow_kernel<<<(DINNER * DMODEL) / 1024, 256, 0, stream>>>(
        out_w[d], owT + (size_t)d * DINNER * DMODEL);
  }
  gemm_lds<true><<<dim3(DMODEL / 128, DINNER / 128, 2), 256, 0, stream>>>(
      wf1, owT, wc, DMODEL, DINNER, 0, 0, 0,
      (size_t)DMODEL * DMODEL, (size_t)DINNER * DMODEL, (size_t)DMODEL * DINNER,
      nullptr);

  for (int dir = 0; dir < 2; dir++) {
    cast_kernel<<<(NROWS_XBC * DMODEL) / 1024, 256, 0, stream>>>(in_w[dir], w_in);
    // in-proj xBC part (in_w rows 1536..3200) -> xbcr
    gemm_lds<true><<<dim3(NTOK / 128, CONVDIM / 128), 256, 0, stream>>>(
        x_bf, w_in + (size_t)DINNER * DMODEL, xbcr, DMODEL, CONVDIM, dir, 0, 0,
        0, 0, 0, nullptr);
    // B/C conv+silu once -> per-chunk blobs
    conv_bc_kernel<<<(NTOK * 16) / 256, 256, 0, stream>>>(
        xbcr, conv_w[dir], conv_b[dir], Bblob, Cblob);
    // chunked SSD
    chunk_intra_kernel<<<BATCHN * HN * NCHUNK, 256, 0, stream>>>(
        xbcr, Bblob, Cblob, conv_w[dir], conv_b[dir], dtbs[dir], dlbs[dir], Dp[dir],
        Yblob, Gblob, laq);
    state_scan_kernel<<<BATCHN * HN * 4, 256, 0, stream>>>(Gblob, laq);
    chunk_inter_kernel<<<BATCHN * HN * NCHUNK, 256, 0, stream>>>(Cblob, dlbs[dir], Gblob, Yblob);
    // in-proj z part (in_w rows 0..1536) -> zbuf (blob region, now dead)
    gemm_lds<true><<<dim3(NTOK / 128, DINNER / 128), 256, 0, stream>>>(
        x_bf, w_in, zbuf, DMODEL, DINNER, dir, 0, 0, 0, 0, 0, nullptr);
    // gated RMSNorm -> ynorm rows (xbcr region, now dead)
    norm_kernel<<<NTOK, 256, 0, stream>>>(Yblob, zbuf, norm_w[dir], ynorm);
    // out-proj + fusion: d_out (+)= ynorm @ wc_dir^T (dir1 un-flips rows, accumulates)
    gemm_lds<false><<<dim3(NTOK / 128, DMODEL / 128), 256, 0, stream>>>(
        ynorm, wc + (size_t)dir * DMODEL * DINNER, d_out, DINNER, DMODEL, 0, dir, dir,
        0, 0, 0, dir == 0 ? fus_b : nullptr);
  }
}

// Round 10
// 886.089 us; speedup vs baseline: 1.0618x; 1.0162x over previous
//
#include <hip/hip_runtime.h>
#include <hip/hip_bf16.h>

// BiMamba: bidirectional Mamba2 forward, MI355X/gfx950.
// Per direction: in-proj (bf16 MFMA GEMM, A-row flip for backward) -> exact
// fp32 dt/log-decay (fused both-dir tiled GEMV, also emits x_bf) -> conv+silu
// for B/C once into per-chunk blobs -> chunked SSD scan (three 64^3 matmuls on
// MFMA) -> z GEMM -> gated RMSNorm -> combined out-proj+fusion GEMM -> d_out.
// GEMM (round-5 form, measured best): 128x128 tile, BK=32, async global->LDS
// (16B), DOUBLE-buffered LDS with ONE barrier per k-step. Round-6 A/B showed
// counted-vmcnt 3-buf is null; round-4 showed XCD swizzle breaks the natural
// x-major L2 residency (xcd = blockIdx.x%8 -> per-XCD A set is 3.1 MB).
// Round-10: dtb/dlb stored h-major [h][NTOK] (chunk kernels' per-lane reads
// become 4-line coalesced instead of 96B-strided 64-line bursts); chunk_inter
// stages the prefix-state B-operand into LDS (was 8 scattered global 16B loads
// on the MFMA critical path).
// Round-9: cast_x fused into dt_fused; both dirs' wc GEMMs batched (gridDim.z).
// Round-8: state_scan split 4x per (b,h) so all 256 CUs participate.
// Round-3: all scalar memory paths in the SSD chain vectorized to 16B (G13).

#define BATCHN 4
#define SEQL 4096
#define DMODEL 768
#define DINNER 1536
#define DSTATE 64
#define HN 24
#define CONVDIM 1664          // DINNER + 2*DSTATE
#define NROWS_XBC 3200        // DINNER + CONVDIM (in_w rows GEMMed; dt rows excluded)
#define NTOK (BATCHN*SEQL)    // 16384
#define NCHUNK 64             // SEQL / 64
#define LS 72                 // LDS stride (shorts) for chunk kernels
#define GBUF (128 * 32)       // one GEMM LDS buffer (shorts)

typedef short v8s __attribute__((ext_vector_type(8)));
typedef unsigned short v8u __attribute__((ext_vector_type(8)));
typedef unsigned short v4u __attribute__((ext_vector_type(4)));
typedef float v4f __attribute__((ext_vector_type(4)));
typedef unsigned int v2u32 __attribute__((ext_vector_type(2)));
typedef __hip_bfloat16 bf16;

__device__ __forceinline__ int flip_row(int r) {
  return (r & ~4095) | (4095 - (r & 4095));
}
__device__ __forceinline__ float us2f(unsigned short u) {
  return __uint_as_float(((unsigned int)u) << 16);
}
__device__ __forceinline__ unsigned short f2us(float f) {
  bf16 b = __float2bfloat16(f);
  return __builtin_bit_cast(unsigned short, b);
}
// async 16B/lane global->LDS; LDS dest = wave-uniform base + lane*16
__device__ __forceinline__ void async16(const unsigned short* g, unsigned short* l) {
  __builtin_amdgcn_global_load_lds(
      (const __attribute__((address_space(1))) unsigned int*)(const void*)g,
      (__attribute__((address_space(3))) unsigned int*)(void*)l, 16, 0, 0);
}

// ---------------- cast kernels (4-wide) ----------------

__global__ void cast_kernel(const float* __restrict__ src, bf16* __restrict__ dst) {
  int idx = blockIdx.x * 256 + threadIdx.x;   // x4 elements
  v4f v = *(const v4f*)(src + (size_t)idx * 4);
  v2u32 o;
  o[0] = (unsigned int)f2us(v[0]) | ((unsigned int)f2us(v[1]) << 16);
  o[1] = (unsigned int)f2us(v[2]) | ((unsigned int)f2us(v[3]) << 16);
  *(v2u32*)((unsigned short*)dst + (size_t)idx * 4) = o;
}

// dst[j*cols+m] = src[j*src_stride+m]  (extract fus_w half), 4-wide (cols%4==0)
__global__ void cast_strided_kernel(const float* __restrict__ src, bf16* __restrict__ dst,
                                    int cols, int src_stride) {
  int idx4 = (blockIdx.x * 256 + threadIdx.x) * 4;
  int j = idx4 / cols, m = idx4 % cols;
  v4f v = *(const v4f*)(src + (size_t)j * src_stride + m);
  v2u32 o;
  o[0] = (unsigned int)f2us(v[0]) | ((unsigned int)f2us(v[1]) << 16);
  o[1] = (unsigned int)f2us(v[2]) | ((unsigned int)f2us(v[3]) << 16);
  *(v2u32*)((unsigned short*)dst + idx4) = o;
}

// dst[k*768+c] = src[c*1536+k] (out_w -> owT); 4 strided reads, 8B write
__global__ void transpose_ow_kernel(const float* __restrict__ src, bf16* __restrict__ dst) {
  int idx4 = (blockIdx.x * 256 + threadIdx.x) * 4;
  int k = idx4 / DMODEL, c0 = idx4 % DMODEL;
  unsigned short u[4];
#pragma unroll
  for (int i = 0; i < 4; i++)
    u[i] = f2us(src[(size_t)(c0 + i) * DINNER + k]);
  v2u32 o;
  o[0] = (unsigned int)u[0] | ((unsigned int)u[1] << 16);
  o[1] = (unsigned int)u[2] | ((unsigned int)u[3] << 16);
  *(v2u32*)((unsigned short*)dst + idx4) = o;
}

// ------- bf16 MFMA GEMM, LDS-staged, double-buffered: C[M,N]=A[M,K]@B[N,K]^T -------
// 128x128 tile, BK=32. Per k-step: issue next tile's 4 async16 into buf^1,
// ds_read+MFMA from buf, ONE __syncthreads (its vmcnt/lgkm drain covers the
// staged loads AFTER compute hid their latency). Natural block order (no
// swizzle) keeps per-XCD A working set L2-resident.
// zsA/zsB/zsC: per-blockIdx.z element strides (0 for normal 2D launches).
// flip_a: per-lane global row reversal (free). Epilogue: bias/flip_c/accum.
template <bool OUT_BF16>
__global__ __launch_bounds__(256) void gemm_lds(
    const bf16* __restrict__ A, const bf16* __restrict__ B, void* __restrict__ C,
    int K, int ldc, int flip_a, int flip_c, int accum,
    size_t zsA, size_t zsB, size_t zsC, const float* __restrict__ bias) {
  __shared__ unsigned short sA[2 * GBUF];
  __shared__ unsigned short sB[2 * GBUF];
  int tid = threadIdx.x;
  int wave = tid >> 6, lane = tid & 63;
  int l15 = lane & 15, quad = lane >> 4;
  int m0 = blockIdx.x * 128, n0 = blockIdx.y * 128;
  int mw = (wave >> 1) * 64, nw = (wave & 1) * 64;
  int zb = blockIdx.z;

  // staging addresses: wave w owns rows [w*32, w*32+32) of each tile
  int srow = wave * 32 + (lane >> 2);
  int scol = (lane & 3) * 8;
  const unsigned short* Ap = (const unsigned short*)A + (size_t)zb * zsA;
  const unsigned short* Bp = (const unsigned short*)B + (size_t)zb * zsB;
  void* Cz = OUT_BF16 ? (void*)((bf16*)C + (size_t)zb * zsC)
                      : (void*)((float*)C + (size_t)zb * zsC);
  int ar0 = m0 + srow, ar1 = m0 + srow + 16;
  if (flip_a) { ar0 = flip_row(ar0); ar1 = flip_row(ar1); }
  const unsigned short* ga0 = Ap + (size_t)ar0 * K + scol;
  const unsigned short* ga1 = Ap + (size_t)ar1 * K + scol;
  const unsigned short* gb0 = Bp + (size_t)(n0 + srow) * K + scol;
  const unsigned short* gb1 = Bp + (size_t)(n0 + srow + 16) * K + scol;
  int lo0 = (wave * 32) * 32;          // wave-uniform LDS offsets (shorts)
  int lo1 = (wave * 32 + 16) * 32;

  v4f acc[4][4];
#pragma unroll
  for (int i = 0; i < 4; i++)
#pragma unroll
    for (int j = 0; j < 4; j++) acc[i][j] = {0.f, 0.f, 0.f, 0.f};

  // prologue: stage k-step 0 into buffer 0
  async16(ga0, &sA[lo0]);
  async16(ga1, &sA[lo1]);
  async16(gb0, &sB[lo0]);
  async16(gb1, &sB[lo1]);
  __syncthreads();

  int nt = K >> 5;
  for (int t = 0; t < nt; t++) {
    int cur = (t & 1) * GBUF;
    if (t + 1 < nt) {           // issue next tile into the other buffer
      int k0 = (t + 1) << 5;
      int nx = ((t + 1) & 1) * GBUF;
      async16(ga0 + k0, &sA[nx + lo0]);
      async16(ga1 + k0, &sA[nx + lo1]);
      async16(gb0 + k0, &sB[nx + lo0]);
      async16(gb1 + k0, &sB[nx + lo1]);
    }
    v8s af[4], bfr[4];
#pragma unroll
    for (int i = 0; i < 4; i++)
      af[i] = *(const v8s*)&sA[cur + (mw + i * 16 + l15) * 32 + quad * 8];
#pragma unroll
    for (int j = 0; j < 4; j++)
      bfr[j] = *(const v8s*)&sB[cur + (nw + j * 16 + l15) * 32 + quad * 8];
#pragma unroll
    for (int i = 0; i < 4; i++)
#pragma unroll
      for (int j = 0; j < 4; j++)
        acc[i][j] = __builtin_amdgcn_mfma_f32_16x16x32_bf16(af[i], bfr[j], acc[i][j], 0, 0, 0);
    __syncthreads();  // drains vmcnt (next tile staged) + protects buf reuse
  }

  float bv[4];
#pragma unroll
  for (int j = 0; j < 4; j++) bv[j] = bias ? bias[n0 + nw + j * 16 + l15] : 0.f;

#pragma unroll
  for (int i = 0; i < 4; i++) {
#pragma unroll
    for (int r2 = 0; r2 < 4; r2++) {
      int row = m0 + mw + i * 16 + quad * 4 + r2;
      int orow = flip_c ? flip_row(row) : row;
#pragma unroll
      for (int j = 0; j < 4; j++) {
        int col = n0 + nw + j * 16 + l15;
        float v = acc[i][j][r2] + bv[j];
        size_t off = (size_t)orow * ldc + col;
        if (OUT_BF16) {
          ((bf16*)Cz)[off] = __float2bfloat16(v);
        } else {
          float* Cf = (float*)Cz;
          if (accum) v += Cf[off];
          Cf[off] = v;
        }
      }
    }
  }
}

// ---------------- fused fp32 dt path (both directions, one x pass) ----------------
// C[16384,48] = x[16384,768] @ W[48,768]^T, W = dt rows of in_w (fwd|bwd).
// Grid (128,2): blockIdx.y = dir. Block: 128 tokens x 24 cols, 256 threads;
// thread = (tok2 = lane, cg = 6-col group) owns tokens {base+tok2, base+64+tok2}
// so each sW read feeds 8 FMAs. acc[2][6] only -> no spill. Single-buffered LDS,
// direct global->LDS staging, unroll pinned (kc: 1, k4: 2) so the scheduler
// cannot hoist a chunk's worth of loads into registers (the round-1 spill).
// Round-9: dir-0 blocks also emit x_bf from the staged registers.
// Round-10: dt/dl outputs stored h-major [h][NTOK] (coalesced chunk reads).
__global__ __launch_bounds__(256) void dt_fused_kernel(
    const float* __restrict__ x, bf16* __restrict__ xbf,
    const float* __restrict__ in_w0, const float* __restrict__ in_w1,
    const float* __restrict__ dt_bias0, const float* __restrict__ dt_bias1,
    const float* __restrict__ A_log0, const float* __restrict__ A_log1,
    float* __restrict__ dt0, float* __restrict__ dl0,
    float* __restrict__ dt1, float* __restrict__ dl1) {
  __shared__ float sXT[64][128];  // [k][token] transposed
  __shared__ float sW[24][64];    // [col][k]
  int tid = threadIdx.x;
  int tok2 = tid & 63, cg = tid >> 6;   // cg owns cols [cg*6, cg*6+6)
  int dir = blockIdx.y;
  int tok_base = blockIdx.x * 128;

  // staging: 2 threads per token, 32 consecutive k-floats each (8x v4f)
  int st_tok = tid >> 1, st_k0 = (tid & 1) * 32;
  const float* xg = x + (size_t)(tok_base + st_tok) * DMODEL + st_k0;
  unsigned short* xbo =
      (unsigned short*)xbf + (size_t)(tok_base + st_tok) * DMODEL + st_k0;
  const float* wb = dir ? in_w1 : in_w0;
  const float* wrow = wb + (size_t)NROWS_XBC * DMODEL;

  float acc0[6], acc1[6];
#pragma unroll
  for (int c = 0; c < 6; c++) { acc0[c] = 0.f; acc1[c] = 0.f; }

#pragma unroll 1
  for (int kc = 0; kc < 12; kc++) {   // 768 / 64
#pragma unroll
    for (int i = 0; i < 8; i++) {
      v4f v = *(const v4f*)(xg + kc * 64 + i * 4);
#pragma unroll
      for (int j = 0; j < 4; j++) sXT[st_k0 + i * 4 + j][st_tok] = v[j];
      if (dir == 0) {   // emit x_bf (identical values to old cast_x_kernel)
        v2u32 o;
        o[0] = (unsigned int)f2us(v[0]) | ((unsigned int)f2us(v[1]) << 16);
        o[1] = (unsigned int)f2us(v[2]) | ((unsigned int)f2us(v[3]) << 16);
        *(v2u32*)(xbo + kc * 64 + i * 4) = o;
      }
    }
    for (int i = tid; i < 24 * 16; i += 256) {
      int col = i >> 4, k4 = i & 15;
      *(v4f*)&sW[col][k4 * 4] =
          *(const v4f*)(wrow + (size_t)col * DMODEL + kc * 64 + k4 * 4);
    }
    __syncthreads();
#pragma unroll 2
    for (int k4 = 0; k4 < 16; k4++) {
      float xa[4], xb[4];
#pragma unroll
      for (int j = 0; j < 4; j++) {
        xa[j] = sXT[k4 * 4 + j][tok2];
        xb[j] = sXT[k4 * 4 + j][tok2 + 64];
      }
#pragma unroll
      for (int c = 0; c < 6; c++) {
        v4f wv = *(const v4f*)&sW[cg * 6 + c][k4 * 4];
#pragma unroll
        for (int j = 0; j < 4; j++) {
          acc0[c] = fmaf(xa[j], wv[j], acc0[c]);
          acc1[c] = fmaf(xb[j], wv[j], acc1[c]);
        }
      }
    }
    __syncthreads();
  }

  // epilogue: exact fp32 softplus / decay (identical formulas; h-major store)
  const float* dtB = dir ? dt_bias1 : dt_bias0;
  const float* Alg = dir ? A_log1 : A_log0;
  float* dto = dir ? dt1 : dt0;
  float* dlo = dir ? dl1 : dl0;
#pragma unroll
  for (int t = 0; t < 2; t++) {
    int r = tok_base + t * 64 + tok2;
    size_t row = dir ? (size_t)flip_row(r) : (size_t)r;
#pragma unroll
    for (int c = 0; c < 6; c++) {
      int h = cg * 6 + c;
      float v = (t ? acc1[c] : acc0[c]) + dtB[h];
      float dtv = (v > 20.f) ? v : log1pf(expf(v));
      dto[(size_t)h * NTOK + row] = dtv;
      dlo[(size_t)h * NTOK + row] = -dtv * expf(Alg[h]);
    }
  }
}

// ---------------- conv+silu for B/C channels -> per-chunk blobs ----------------
// Thread = (token, 8-channel octet): 4x v8u taps, 8 outputs, one 16B store.
__global__ void conv_bc_kernel(const bf16* __restrict__ xbcr,
                               const float* __restrict__ conv_w,
                               const float* __restrict__ conv_b,
                               bf16* __restrict__ Bblob, bf16* __restrict__ Cblob) {
  int idx = blockIdx.x * 256 + threadIdx.x;  // NTOK*16
  int token = idx >> 4, oct = idx & 15;
  int b = token >> 12, l = token & 4095, c = l >> 6, s = l & 63;
  int ch0 = 1536 + oct * 8;
  const unsigned short* xp = (const unsigned short*)xbcr;
  v8u tv[4];
#pragma unroll
  for (int j = 0; j < 4; j++) {
    int ls = l - 3 + j;
    v8u z = {0, 0, 0, 0, 0, 0, 0, 0};
    tv[j] = z;
    if (ls >= 0)
      tv[j] = *(const v8u*)(xp + (size_t)((b << 12) | ls) * CONVDIM + ch0);
  }
  v8u ov;
#pragma unroll
  for (int e = 0; e < 8; e++) {
    int ch = ch0 + e;
    const float* w4 = conv_w + ch * 4;
    float acc = conv_b[ch];
#pragma unroll
    for (int j = 0; j < 4; j++) acc += us2f(tv[j][e]) * w4[j];
    ov[e] = f2us(acc / (1.f + __expf(-acc)));
  }
  size_t base = ((size_t)((b * 64 + c) * 64 + s)) * 64;
  int ch7 = oct * 8;
  if (ch7 < 64) *(v8u*)((unsigned short*)Bblob + base + ch7) = ov;
  else          *(v8u*)((unsigned short*)Cblob + base + ch7 - 64) = ov;
}

// ---------------- chunked SSD: intra-chunk kernel (MFMA) ----------------
__global__ __launch_bounds__(256) void chunk_intra_kernel(
    const bf16* __restrict__ xbcr, const bf16* __restrict__ Bblob,
    const bf16* __restrict__ Cblob, const float* __restrict__ conv_w,
    const float* __restrict__ conv_b, const float* __restrict__ dtb,
    const float* __restrict__ dlb, const float* __restrict__ Dp,
    bf16* __restrict__ Yblob, bf16* __restrict__ Gblob, float* __restrict__ laq) {
  int blk = blockIdx.x;
  int c = blk & 63, bh = blk >> 6;
  int h = bh % HN, b = bh / HN;
  int tid = threadIdx.x, lane = tid & 63, wv = tid >> 6;
  int l15 = lane & 15, quad = lane >> 4;
  int tok0 = b * SEQL + c * 64;

  __shared__ unsigned short sXT[64][LS];  // [p][s]
  __shared__ unsigned short sB [64][LS];  // [s][n]; later sY [t][p]
  __shared__ unsigned short sBT[64][LS];  // [n][s] dG-scaled
  __shared__ unsigned short sC [64][LS];  // [t][n]; later sG [p][n]
  // rawX stride 72 shorts (144B): v8u rows 16B-aligned; dead before W written
  __shared__ union { unsigned short rawX[67][72]; unsigned short W[64][LS]; } sU;
  __shared__ float sla[64], sdt[64], sdG[64];

  // rawX staging: 67 rows x 8 v8u = 536 16B units (coalesced: 8 thr/row)
  for (int i = tid; i < 536; i += 256) {
    int r = i >> 3, j = i & 7;
    int l = c * 64 + r - 3;
    v8u v = {0, 0, 0, 0, 0, 0, 0, 0};
    if (l >= 0)
      v = *(const v8u*)((const unsigned short*)xbcr +
                        (size_t)(b * SEQL + l) * CONVDIM + h * 64 + j * 8);
    *(v8u*)&sU.rawX[r][j * 8] = v;
  }
  {
    const v8u* gB = (const v8u*)((const unsigned short*)Bblob + ((size_t)(b * 64 + c)) * 4096);
    const v8u* gC = (const v8u*)((const unsigned short*)Cblob + ((size_t)(b * 64 + c)) * 4096);
    int r0 = tid >> 3, g0 = tid & 7;
#pragma unroll
    for (int it = 0; it < 2; it++) {
      int row = r0 + it * 32;
      *(v8u*)&sB[row][g0 * 8] = gB[row * 8 + g0];
      *(v8u*)&sC[row][g0 * 8] = gC[row * 8 + g0];
    }
  }
  if (wv == 0) {  // log-decay prefix scan (h-major inputs: coalesced)
    float dtv = dtb[(size_t)h * NTOK + tok0 + lane];
    float lg = dlb[(size_t)h * NTOK + tok0 + lane];
#pragma unroll
    for (int d = 1; d < 64; d <<= 1) {
      float o = __shfl_up(lg, d);
      if (lane >= d) lg += o;
    }
    sla[lane] = lg;
    sdt[lane] = dtv;
    float la63 = __shfl(lg, 63);
    sdG[lane] = __expf(la63 - lg) * dtv;
    if (lane == 63) laq[blk] = __expf(la63);
  }
  __syncthreads();

  float Dh = Dp[h];
  {
    int s = lane;
    // conv+silu: wave wv owns p in [wv*16, wv*16+16) as 2 octets; 4x v8u reads
#pragma unroll
    for (int o = 0; o < 2; o++) {
      int p0 = (wv * 2 + o) * 8;
      v8u r0 = *(const v8u*)&sU.rawX[s + 0][p0];
      v8u r1 = *(const v8u*)&sU.rawX[s + 1][p0];
      v8u r2 = *(const v8u*)&sU.rawX[s + 2][p0];
      v8u r3 = *(const v8u*)&sU.rawX[s + 3][p0];
#pragma unroll
      for (int pp = 0; pp < 8; pp++) {
        int ch = h * 64 + p0 + pp;
        const float* w4 = conv_w + ch * 4;
        float acc = conv_b[ch] + us2f(r0[pp]) * w4[0] + us2f(r1[pp]) * w4[1] +
                    us2f(r2[pp]) * w4[2] + us2f(r3[pp]) * w4[3];
        sXT[p0 + pp][s] = f2us(acc / (1.f + __expf(-acc)));
      }
    }
#pragma unroll
    for (int it = 0; it < 16; it++) {
      int n = wv + it * 4;
      sBT[n][s] = f2us(us2f(sB[s][n]) * sdG[s]);
    }
  }
  __syncthreads();

  {  // W = C @ B^T, masked decay
    v4f acc[4];
#pragma unroll
    for (int j = 0; j < 4; j++) acc[j] = {0.f, 0.f, 0.f, 0.f};
    __builtin_amdgcn_s_setprio(1);
#pragma unroll
    for (int k0 = 0; k0 < 2; k0++) {
      v8s a = *(const v8s*)&sC[16 * wv + l15][k0 * 32 + quad * 8];
#pragma unroll
      for (int j = 0; j < 4; j++) {
        v8s bb = *(const v8s*)&sB[16 * j + l15][k0 * 32 + quad * 8];
        acc[j] = __builtin_amdgcn_mfma_f32_16x16x32_bf16(a, bb, acc[j], 0, 0, 0);
      }
    }
    __builtin_amdgcn_s_setprio(0);
    float lat[4];
#pragma unroll
    for (int r = 0; r < 4; r++) lat[r] = sla[16 * wv + quad * 4 + r];
#pragma unroll
    for (int j = 0; j < 4; j++) {
      int s = 16 * j + l15;
      float las = sla[s], dts = sdt[s];
#pragma unroll
      for (int r = 0; r < 4; r++) {
        int t = 16 * wv + quad * 4 + r;
        float w = (s <= t) ? __expf(lat[r] - las) * dts * acc[j][r] : 0.f;
        sU.W[t][s] = f2us(w);
      }
    }
  }
  __syncthreads();

  {  // y = W @ X + D*x; G = X @ BT
    v4f ya[4], ga[4];
#pragma unroll
    for (int j = 0; j < 4; j++) {
      ya[j] = {0.f, 0.f, 0.f, 0.f};
      ga[j] = {0.f, 0.f, 0.f, 0.f};
    }
    __builtin_amdgcn_s_setprio(1);
#pragma unroll
    for (int k0 = 0; k0 < 2; k0++) {
      v8s aw = *(const v8s*)&sU.W[16 * wv + l15][k0 * 32 + quad * 8];
      v8s ax = *(const v8s*)&sXT[16 * wv + l15][k0 * 32 + quad * 8];
#pragma unroll
      for (int j = 0; j < 4; j++) {
        v8s bx = *(const v8s*)&sXT[16 * j + l15][k0 * 32 + quad * 8];
        v8s bt = *(const v8s*)&sBT[16 * j + l15][k0 * 32 + quad * 8];
        ya[j] = __builtin_amdgcn_mfma_f32_16x16x32_bf16(aw, bx, ya[j], 0, 0, 0);
        ga[j] = __builtin_amdgcn_mfma_f32_16x16x32_bf16(ax, bt, ga[j], 0, 0, 0);
      }
    }
    __builtin_amdgcn_s_setprio(0);
#pragma unroll
    for (int j = 0; j < 4; j++) {
      int col = 16 * j + l15;
#pragma unroll
      for (int r = 0; r < 4; r++) {
        int row = 16 * wv + quad * 4 + r;
        float yv = ya[j][r] + Dh * us2f(sXT[col][row]);
        sB[row][col] = f2us(yv);
        sC[row][col] = f2us(ga[j][r]);
      }
    }
  }
  __syncthreads();

  {  // blob out: 2 passes of 16B
    v8u* gY = (v8u*)(Yblob + (size_t)blk * 4096);
    v8u* gG = (v8u*)(Gblob + (size_t)blk * 4096);
#pragma unroll
    for (int it = 0; it < 2; it++) {
      int i = tid + it * 256;
      int row = i >> 3, j = i & 7;
      gY[row * 8 + j] = *(const v8u*)&sB[row][j * 8];
      gG[row * 8 + j] = *(const v8u*)&sC[row][j * 8];
    }
  }
}

// ---------------- chunked SSD: inter-chunk state recurrence ----------------
// 4 blocks per (b,h) so all 256 CUs participate (384 blocks total).
__global__ __launch_bounds__(256) void state_scan_kernel(
    bf16* __restrict__ blob, const float* __restrict__ laq) {
  int blk = blockIdx.x;
  int bh = blk >> 2, qq = blk & 3;
  int tid = threadIdx.x;
  size_t base = (size_t)bh * 64 * 4096 +
                (size_t)(qq * 16 + (tid >> 4)) * 64 + (size_t)(tid & 15) * 4;
  float S[4];
#pragma unroll
  for (int i = 0; i < 4; i++) S[i] = 0.f;
  for (int c = 0; c < 64; c++) {
    float q = laq[bh * 64 + c];
    unsigned short* gp = (unsigned short*)blob + base + (size_t)c * 4096;
    v4u ga = *(v4u*)gp;
    v4u pa;
#pragma unroll
    for (int i = 0; i < 4; i++) pa[i] = f2us(S[i]);
    *(v4u*)gp = pa;
#pragma unroll
    for (int i = 0; i < 4; i++) S[i] = q * S[i] + us2f(ga[i]);
  }
}

// ---------------- chunked SSD: inter-chunk y contribution (MFMA) ----------------
// Round-10: prefix state staged into LDS (sS) during the coalesced staging
// phase -- the MFMA B-operand no longer issues scattered global loads.
__global__ __launch_bounds__(256) void chunk_inter_kernel(
    const bf16* __restrict__ Cblob, const float* __restrict__ dlb,
    const bf16* __restrict__ blob, bf16* __restrict__ Yblob) {
  int blk = blockIdx.x;
  int c = blk & 63, bh = blk >> 6;
  int h = bh % HN, b = bh / HN;
  int tid = threadIdx.x, lane = tid & 63, wv = tid >> 6;
  int l15 = lane & 15, quad = lane >> 4;
  int tok0 = b * SEQL + c * 64;

  __shared__ unsigned short sC[64][LS];
  __shared__ unsigned short sS[64][LS];
  __shared__ unsigned short sY[64][LS];
  __shared__ float sel[64];

  {
    const v8u* gC = (const v8u*)((const unsigned short*)Cblob + ((size_t)(b * 64 + c)) * 4096);
    const v8u* gS = (const v8u*)((const unsigned short*)blob + (size_t)blk * 4096);
    int r0 = tid >> 3, g0 = tid & 7;
#pragma unroll
    for (int it = 0; it < 2; it++) {
      int row = r0 + it * 32;
      *(v8u*)&sC[row][g0 * 8] = gC[row * 8 + g0];
      *(v8u*)&sS[row][g0 * 8] = gS[row * 8 + g0];
    }
  }
  if (wv == 0) {  // h-major dlb: coalesced
    float lg = dlb[(size_t)h * NTOK + tok0 + lane];
#pragma unroll
    for (int d = 1; d < 64; d <<= 1) {
      float o = __shfl_up(lg, d);
      if (lane >= d) lg += o;
    }
    sel[lane] = __expf(lg);
  }
  __syncthreads();
  {
    v4f acc[4];
#pragma unroll
    for (int j = 0; j < 4; j++) acc[j] = {0.f, 0.f, 0.f, 0.f};
    __builtin_amdgcn_s_setprio(1);
#pragma unroll
    for (int k0 = 0; k0 < 2; k0++) {
      v8s a = *(const v8s*)&sC[16 * wv + l15][k0 * 32 + quad * 8];
#pragma unroll
      for (int j = 0; j < 4; j++) {
        v8s bS = *(const v8s*)&sS[16 * j + l15][k0 * 32 + quad * 8];
        acc[j] = __builtin_amdgcn_mfma_f32_16x16x32_bf16(a, bS, acc[j], 0, 0, 0);
      }
    }
    __builtin_amdgcn_s_setprio(0);
    float selt[4];
#pragma unroll
    for (int r = 0; r < 4; r++) selt[r] = sel[16 * wv + quad * 4 + r];
#pragma unroll
    for (int j = 0; j < 4; j++)
#pragma unroll
      for (int r = 0; r < 4; r++)
        sY[16 * wv + quad * 4 + r][16 * j + l15] = f2us(selt[r] * acc[j][r]);
  }
  __syncthreads();
  {  // Y RMW: 2 passes of 16B
    v8u* gY = (v8u*)(Yblob + (size_t)blk * 4096);
#pragma unroll
    for (int it = 0; it < 2; it++) {
      int i = tid + it * 256;
      int row = i >> 3, j = i & 7;
      v8u old = gY[row * 8 + j];
      v8u add = *(const v8u*)&sY[row][j * 8];
      v8u outv;
#pragma unroll
      for (int e = 0; e < 8; e++) outv[e] = f2us(us2f(old[e]) + us2f(add[e]));
      gY[row * 8 + j] = outv;
    }
  }
}

// ---------------- gated RMSNorm: blob y + z rows -> ynorm rows ----------------
// Paired (4B) loads/stores: 3 iterations of 2 channels.
__global__ __launch_bounds__(256) void norm_kernel(
    const bf16* __restrict__ Yblob, const bf16* __restrict__ z,
    const float* __restrict__ norm_w, bf16* __restrict__ out) {
  int token = blockIdx.x;
  int tid = threadIdx.x;
  int b = token >> 12, l = token & 4095, c = l >> 6, t = l & 63;
  const unsigned short* zp = (const unsigned short*)z + (size_t)token * DINNER;
  float vals[6];
  float ss = 0.f;
#pragma unroll
  for (int i = 0; i < 3; i++) {
    int q = tid + i * 256;          // pair index 0..767
    int ch = q * 2;
    int hh = ch >> 6, p = ch & 63;  // p even
    size_t yi = ((((size_t)(b * HN + hh)) * 64 + c) * 64 + t) * 64 + p;
    unsigned int yv2 = *(const unsigned int*)((const unsigned short*)Yblob + yi);
    unsigned int zv2 = *(const unsigned int*)(zp + ch);
#pragma unroll
    for (int e = 0; e < 2; e++) {
      float yv = us2f((unsigned short)((yv2 >> (16 * e)) & 0xffff));
      float zv = us2f((unsigned short)((zv2 >> (16 * e)) & 0xffff));
      float g = zv / (1.f + __expf(-zv));
      float v = yv * g;
      vals[i * 2 + e] = v;
      ss += v * v;
    }
  }
  for (int off = 32; off > 0; off >>= 1) ss += __shfl_down(ss, off);
  __shared__ float sred[4];
  if ((tid & 63) == 0) sred[tid >> 6] = ss;
  __syncthreads();
  float tot = sred[0] + sred[1] + sred[2] + sred[3];
  float scale = rsqrtf(tot / (float)DINNER + 1e-5f);
#pragma unroll
  for (int i = 0; i < 3; i++) {
    int q = tid + i * 256;
    int ch = q * 2;
    unsigned int o =
        (unsigned int)f2us(vals[i * 2] * scale * norm_w[ch]) |
        ((unsigned int)f2us(vals[i * 2 + 1] * scale * norm_w[ch + 1]) << 16);
    *(unsigned int*)((unsigned short*)out + (size_t)token * DINNER + ch) = o;
  }
}

// ---------------- launch ----------------
extern "C" void kernel_launch(void* const* d_in, const int* in_sizes, int n_in,
                              void* d_out, int out_size, void* d_ws, size_t ws_size,
                              hipStream_t stream) {
  const float* x = (const float*)d_in[0];
  const float* fus_w = (const float*)d_in[1];
  const float* fus_b = (const float*)d_in[2];
  const float* in_w[2] = {(const float*)d_in[3], (const float*)d_in[11]};
  const float* conv_w[2] = {(const float*)d_in[4], (const float*)d_in[12]};
  const float* conv_b[2] = {(const float*)d_in[5], (const float*)d_in[13]};
  const float* dt_bias[2] = {(const float*)d_in[6], (const float*)d_in[14]};
  const float* A_log[2] = {(const float*)d_in[7], (const float*)d_in[15]};
  const float* Dp[2] = {(const float*)d_in[8], (const float*)d_in[16]};
  const float* norm_w[2] = {(const float*)d_in[9], (const float*)d_in[17]};
  const float* out_w[2] = {(const float*)d_in[10], (const float*)d_in[18]};
  (void)in_sizes; (void)n_in;

  char* ws = (char*)d_ws;
  size_t off = 0;
  auto alloc = [&](size_t bytes) {
    size_t o = off;
    off = (off + bytes + 255) & ~(size_t)255;
    return o;
  };
  bf16* x_bf  = (bf16*)(ws + alloc((size_t)NTOK * DMODEL * 2));              // 25.2 MB
  bf16* w_in  = (bf16*)(ws + alloc((size_t)NROWS_XBC * DMODEL * 2));         //  4.9 MB
  bf16* wf1   = (bf16*)(ws + alloc((size_t)2 * DMODEL * DMODEL * 2));        //  2.4 MB (x2 dirs)
  bf16* owT   = (bf16*)(ws + alloc((size_t)2 * DINNER * DMODEL * 2));        //  4.7 MB (x2 dirs)
  bf16* wc    = (bf16*)(ws + alloc((size_t)2 * DMODEL * DINNER * 2));        //  4.7 MB (x2 dirs)
  bf16* xbcr  = (bf16*)(ws + alloc((size_t)NTOK * CONVDIM * 2));             // 54.5 MB (ynorm aliases)
  float* dtb0 = (float*)(ws + alloc((size_t)NTOK * HN * 4));                 //  1.6 MB
  float* dlb0 = (float*)(ws + alloc((size_t)NTOK * HN * 4));                 //  1.6 MB
  float* dtb1 = (float*)(ws + alloc((size_t)NTOK * HN * 4));                 //  1.6 MB
  float* dlb1 = (float*)(ws + alloc((size_t)NTOK * HN * 4));                 //  1.6 MB
  float* laq  = (float*)(ws + alloc((size_t)BATCHN * HN * NCHUNK * 4));      //  0.02 MB
  bf16* Bblob = (bf16*)(ws + alloc((size_t)NTOK * DSTATE * 2));              //  2.1 MB
  bf16* Cblob = (bf16*)(ws + alloc((size_t)NTOK * DSTATE * 2));              //  2.1 MB
  bf16* Gblob = (bf16*)(ws + alloc((size_t)NTOK * DINNER * 2));              // 50.3 MB (z aliases)
  bf16* Yblob = (bf16*)(ws + alloc((size_t)NTOK * DINNER * 2));              // 50.3 MB
  bf16* zbuf  = Gblob;  // z GEMM output reuses G/prefix blob (dead after chunk_inter)
  bf16* ynorm = xbcr;   // normalized y reuses xbcr (dead after chunk_inter)
  float* dtbs[2] = {dtb0, dtb1};
  float* dlbs[2] = {dlb0, dlb1};

  if (ws_size < off) {  // diagnostic: clean absmax(=max|ref|) failure, not a crash
    hipMemsetAsync(d_out, 0, (size_t)out_size * 4, stream);
    return;
  }

  // exact fp32 dt + log-decay, both directions in one x pass; also emits x_bf
  dt_fused_kernel<<<dim3(NTOK / 128, 2), 256, 0, stream>>>(
      x, x_bf, in_w[0], in_w[1], dt_bias[0], dt_bias[1], A_log[0], A_log[1],
      dtb0, dlb0, dtb1, dlb1);

  // combined weights wc_d = fus_half_d @ out_w_d (768x1536), both dirs batched
  for (int d = 0; d < 2; d++) {
    cast_strided_kernel<<<(DMODEL * DMODEL) / 1024, 256, 0, stream>>>(
        fus_w + d * DMODEL, wf1 + (size_t)d * DMODEL * DMODEL, DMODEL, 2 * DMODEL);
    transpose_ow_kernel<<<(DINNER * DMODEL) / 1024, 256, 0, stream>>>(
        out_w[d], owT + (size_t)d * DINNER * DMODEL);
  }
  gemm_lds<true><<<dim3(DMODEL / 128, DINNER / 128, 2), 256, 0, stream>>>(
      wf1, owT, wc, DMODEL, DINNER, 0, 0, 0,
      (size_t)DMODEL * DMODEL, (size_t)DINNER * DMODEL, (size_t)DMODEL * DINNER,
      nullptr);

  for (int dir = 0; dir < 2; dir++) {
    cast_kernel<<<(NROWS_XBC * DMODEL) / 1024, 256, 0, stream>>>(in_w[dir], w_in);
    // in-proj xBC part (in_w rows 1536..3200) -> xbcr
    gemm_lds<true><<<dim3(NTOK / 128, CONVDIM / 128), 256, 0, stream>>>(
        x_bf, w_in + (size_t)DINNER * DMODEL, xbcr, DMODEL, CONVDIM, dir, 0, 0,
        0, 0, 0, nullptr);
    // B/C conv+silu once -> per-chunk blobs
    conv_bc_kernel<<<(NTOK * 16) / 256, 256, 0, stream>>>(
        xbcr, conv_w[dir], conv_b[dir], Bblob, Cblob);
    // chunked SSD
    chunk_intra_kernel<<<BATCHN * HN * NCHUNK, 256, 0, stream>>>(
        xbcr, Bblob, Cblob, conv_w[dir], conv_b[dir], dtbs[dir], dlbs[dir], Dp[dir],
        Yblob, Gblob, laq);
    state_scan_kernel<<<BATCHN * HN * 4, 256, 0, stream>>>(Gblob, laq);
    chunk_inter_kernel<<<BATCHN * HN * NCHUNK, 256, 0, stream>>>(Cblob, dlbs[dir], Gblob, Yblob);
    // in-proj z part (in_w rows 0..1536) -> zbuf (blob region, now dead)
    gemm_lds<true><<<dim3(NTOK / 128, DINNER / 128), 256, 0, stream>>>(
        x_bf, w_in, zbuf, DMODEL, DINNER, dir, 0, 0, 0, 0, 0, nullptr);
    // gated RMSNorm -> ynorm rows (xbcr region, now dead)
    norm_kernel<<<NTOK, 256, 0, stream>>>(Yblob, zbuf, norm_w[dir], ynorm);
    // out-proj + fusion: d_out (+)= ynorm @ wc_dir^T (dir1 un-flips rows, accumulates)
    gemm_lds<false><<<dim3(NTOK / 128, DMODEL / 128), 256, 0, stream>>>(
        ynorm, wc + (size_t)dir * DMODEL * DINNER, d_out, DINNER, DMODEL, 0, dir, dir,
        0, 0, 0, dir == 0 ? fus_b : nullptr);
  }
}

// Round 11
// 867.781 us; speedup vs baseline: 1.0842x; 1.0211x over previous
//
#include <hip/hip_runtime.h>
#include <hip/hip_bf16.h>

// BiMamba: bidirectional Mamba2 forward, MI355X/gfx950.
// Per direction: in-proj (bf16 MFMA GEMM, A-row flip for backward) -> exact
// fp32 dt/log-decay (fused both-dir tiled GEMV, also emits x_bf) -> conv+silu
// for B/C once into per-chunk blobs -> chunked SSD scan (three 64^3 matmuls on
// MFMA) -> z GEMM -> gated RMSNorm -> out-proj+fusion GEMM -> d_out.
// GEMM (round-5 form, measured best): 128x128 tile, BK=32, async global->LDS
// (16B), DOUBLE-buffered LDS with ONE barrier per k-step. Round-6 A/B showed
// counted-vmcnt 3-buf is null; round-4 showed XCD swizzle breaks the natural
// x-major L2 residency (xcd = blockIdx.x%8 -> per-XCD A set is 3.1 MB).
// Round-11: if workspace permits, the two out-proj GEMMs become ONE K=3072
// GEMM over concatenated operands (ynormC[NTOK][3072], wcC[768][3072]):
// norm(dir1) writes its half at flip(token) rows (bakes in the old flip_c),
// d_out is written once with bias -- no fp32 RMW (-100MB, -1 launch). Falls
// back to the round-10 path at runtime if ws_size is insufficient.
// Round-10: dtb/dlb h-major [h][NTOK]; chunk_inter stages prefix state in LDS.
// Round-9: cast_x fused into dt_fused; wc GEMMs batched (gridDim.z).
// Round-8: state_scan split 4x per (b,h) so all 256 CUs participate.
// Round-3: all scalar memory paths in the SSD chain vectorized to 16B (G13).

#define BATCHN 4
#define SEQL 4096
#define DMODEL 768
#define DINNER 1536
#define DSTATE 64
#define HN 24
#define CONVDIM 1664          // DINNER + 2*DSTATE
#define NROWS_XBC 3200        // DINNER + CONVDIM (in_w rows GEMMed; dt rows excluded)
#define NTOK (BATCHN*SEQL)    // 16384
#define NCHUNK 64             // SEQL / 64
#define LS 72                 // LDS stride (shorts) for chunk kernels
#define GBUF (128 * 32)       // one GEMM LDS buffer (shorts)

typedef short v8s __attribute__((ext_vector_type(8)));
typedef unsigned short v8u __attribute__((ext_vector_type(8)));
typedef unsigned short v4u __attribute__((ext_vector_type(4)));
typedef float v4f __attribute__((ext_vector_type(4)));
typedef unsigned int v2u32 __attribute__((ext_vector_type(2)));
typedef __hip_bfloat16 bf16;

__device__ __forceinline__ int flip_row(int r) {
  return (r & ~4095) | (4095 - (r & 4095));
}
__device__ __forceinline__ float us2f(unsigned short u) {
  return __uint_as_float(((unsigned int)u) << 16);
}
__device__ __forceinline__ unsigned short f2us(float f) {
  bf16 b = __float2bfloat16(f);
  return __builtin_bit_cast(unsigned short, b);
}
// async 16B/lane global->LDS; LDS dest = wave-uniform base + lane*16
__device__ __forceinline__ void async16(const unsigned short* g, unsigned short* l) {
  __builtin_amdgcn_global_load_lds(
      (const __attribute__((address_space(1))) unsigned int*)(const void*)g,
      (__attribute__((address_space(3))) unsigned int*)(void*)l, 16, 0, 0);
}

// ---------------- cast kernels (4-wide) ----------------

__global__ void cast_kernel(const float* __restrict__ src, bf16* __restrict__ dst) {
  int idx = blockIdx.x * 256 + threadIdx.x;   // x4 elements
  v4f v = *(const v4f*)(src + (size_t)idx * 4);
  v2u32 o;
  o[0] = (unsigned int)f2us(v[0]) | ((unsigned int)f2us(v[1]) << 16);
  o[1] = (unsigned int)f2us(v[2]) | ((unsigned int)f2us(v[3]) << 16);
  *(v2u32*)((unsigned short*)dst + (size_t)idx * 4) = o;
}

// dst[j*cols+m] = src[j*src_stride+m]  (extract fus_w half), 4-wide (cols%4==0)
__global__ void cast_strided_kernel(const float* __restrict__ src, bf16* __restrict__ dst,
                                    int cols, int src_stride) {
  int idx4 = (blockIdx.x * 256 + threadIdx.x) * 4;
  int j = idx4 / cols, m = idx4 % cols;
  v4f v = *(const v4f*)(src + (size_t)j * src_stride + m);
  v2u32 o;
  o[0] = (unsigned int)f2us(v[0]) | ((unsigned int)f2us(v[1]) << 16);
  o[1] = (unsigned int)f2us(v[2]) | ((unsigned int)f2us(v[3]) << 16);
  *(v2u32*)((unsigned short*)dst + idx4) = o;
}

// dst[k*768+c] = src[c*1536+k] (out_w -> owT); 4 strided reads, 8B write
__global__ void transpose_ow_kernel(const float* __restrict__ src, bf16* __restrict__ dst) {
  int idx4 = (blockIdx.x * 256 + threadIdx.x) * 4;
  int k = idx4 / DMODEL, c0 = idx4 % DMODEL;
  unsigned short u[4];
#pragma unroll
  for (int i = 0; i < 4; i++)
    u[i] = f2us(src[(size_t)(c0 + i) * DINNER + k]);
  v2u32 o;
  o[0] = (unsigned int)u[0] | ((unsigned int)u[1] << 16);
  o[1] = (unsigned int)u[2] | ((unsigned int)u[3] << 16);
  *(v2u32*)((unsigned short*)dst + idx4) = o;
}

// ------- bf16 MFMA GEMM, LDS-staged, double-buffered: C[M,N]=A[M,K]@B[N,K]^T -------
// 128x128 tile, BK=32. Per k-step: issue next tile's 4 async16 into buf^1,
// ds_read+MFMA from buf, ONE __syncthreads (its vmcnt/lgkm drain covers the
// staged loads AFTER compute hid their latency). Natural block order (no
// swizzle) keeps per-XCD A working set L2-resident.
// zsA/zsB/zsC: per-blockIdx.z element strides (0 for normal 2D launches);
// zsC doubles as a column offset when ldc spans both z-slices.
// flip_a: per-lane global row reversal (free). Epilogue: bias/flip_c/accum.
template <bool OUT_BF16>
__global__ __launch_bounds__(256) void gemm_lds(
    const bf16* __restrict__ A, const bf16* __restrict__ B, void* __restrict__ C,
    int K, int ldc, int flip_a, int flip_c, int accum,
    size_t zsA, size_t zsB, size_t zsC, const float* __restrict__ bias) {
  __shared__ unsigned short sA[2 * GBUF];
  __shared__ unsigned short sB[2 * GBUF];
  int tid = threadIdx.x;
  int wave = tid >> 6, lane = tid & 63;
  int l15 = lane & 15, quad = lane >> 4;
  int m0 = blockIdx.x * 128, n0 = blockIdx.y * 128;
  int mw = (wave >> 1) * 64, nw = (wave & 1) * 64;
  int zb = blockIdx.z;

  // staging addresses: wave w owns rows [w*32, w*32+32) of each tile
  int srow = wave * 32 + (lane >> 2);
  int scol = (lane & 3) * 8;
  const unsigned short* Ap = (const unsigned short*)A + (size_t)zb * zsA;
  const unsigned short* Bp = (const unsigned short*)B + (size_t)zb * zsB;
  void* Cz = OUT_BF16 ? (void*)((bf16*)C + (size_t)zb * zsC)
                      : (void*)((float*)C + (size_t)zb * zsC);
  int ar0 = m0 + srow, ar1 = m0 + srow + 16;
  if (flip_a) { ar0 = flip_row(ar0); ar1 = flip_row(ar1); }
  const unsigned short* ga0 = Ap + (size_t)ar0 * K + scol;
  const unsigned short* ga1 = Ap + (size_t)ar1 * K + scol;
  const unsigned short* gb0 = Bp + (size_t)(n0 + srow) * K + scol;
  const unsigned short* gb1 = Bp + (size_t)(n0 + srow + 16) * K + scol;
  int lo0 = (wave * 32) * 32;          // wave-uniform LDS offsets (shorts)
  int lo1 = (wave * 32 + 16) * 32;

  v4f acc[4][4];
#pragma unroll
  for (int i = 0; i < 4; i++)
#pragma unroll
    for (int j = 0; j < 4; j++) acc[i][j] = {0.f, 0.f, 0.f, 0.f};

  // prologue: stage k-step 0 into buffer 0
  async16(ga0, &sA[lo0]);
  async16(ga1, &sA[lo1]);
  async16(gb0, &sB[lo0]);
  async16(gb1, &sB[lo1]);
  __syncthreads();

  int nt = K >> 5;
  for (int t = 0; t < nt; t++) {
    int cur = (t & 1) * GBUF;
    if (t + 1 < nt) {           // issue next tile into the other buffer
      int k0 = (t + 1) << 5;
      int nx = ((t + 1) & 1) * GBUF;
      async16(ga0 + k0, &sA[nx + lo0]);
      async16(ga1 + k0, &sA[nx + lo1]);
      async16(gb0 + k0, &sB[nx + lo0]);
      async16(gb1 + k0, &sB[nx + lo1]);
    }
    v8s af[4], bfr[4];
#pragma unroll
    for (int i = 0; i < 4; i++)
      af[i] = *(const v8s*)&sA[cur + (mw + i * 16 + l15) * 32 + quad * 8];
#pragma unroll
    for (int j = 0; j < 4; j++)
      bfr[j] = *(const v8s*)&sB[cur + (nw + j * 16 + l15) * 32 + quad * 8];
#pragma unroll
    for (int i = 0; i < 4; i++)
#pragma unroll
      for (int j = 0; j < 4; j++)
        acc[i][j] = __builtin_amdgcn_mfma_f32_16x16x32_bf16(af[i], bfr[j], acc[i][j], 0, 0, 0);
    __syncthreads();  // drains vmcnt (next tile staged) + protects buf reuse
  }

  float bv[4];
#pragma unroll
  for (int j = 0; j < 4; j++) bv[j] = bias ? bias[n0 + nw + j * 16 + l15] : 0.f;

#pragma unroll
  for (int i = 0; i < 4; i++) {
#pragma unroll
    for (int r2 = 0; r2 < 4; r2++) {
      int row = m0 + mw + i * 16 + quad * 4 + r2;
      int orow = flip_c ? flip_row(row) : row;
#pragma unroll
      for (int j = 0; j < 4; j++) {
        int col = n0 + nw + j * 16 + l15;
        float v = acc[i][j][r2] + bv[j];
        size_t off = (size_t)orow * ldc + col;
        if (OUT_BF16) {
          ((bf16*)Cz)[off] = __float2bfloat16(v);
        } else {
          float* Cf = (float*)Cz;
          if (accum) v += Cf[off];
          Cf[off] = v;
        }
      }
    }
  }
}

// ---------------- fused fp32 dt path (both directions, one x pass) ----------------
// C[16384,48] = x[16384,768] @ W[48,768]^T, W = dt rows of in_w (fwd|bwd).
// Grid (128,2): blockIdx.y = dir. Block: 128 tokens x 24 cols, 256 threads;
// thread = (tok2 = lane, cg = 6-col group) owns tokens {base+tok2, base+64+tok2}
// so each sW read feeds 8 FMAs. acc[2][6] only -> no spill. Single-buffered LDS,
// direct global->LDS staging, unroll pinned (kc: 1, k4: 2) so the scheduler
// cannot hoist a chunk's worth of loads into registers (the round-1 spill).
// Round-9: dir-0 blocks also emit x_bf from the staged registers.
// Round-10: dt/dl outputs stored h-major [h][NTOK] (coalesced chunk reads).
__global__ __launch_bounds__(256) void dt_fused_kernel(
    const float* __restrict__ x, bf16* __restrict__ xbf,
    const float* __restrict__ in_w0, const float* __restrict__ in_w1,
    const float* __restrict__ dt_bias0, const float* __restrict__ dt_bias1,
    const float* __restrict__ A_log0, const float* __restrict__ A_log1,
    float* __restrict__ dt0, float* __restrict__ dl0,
    float* __restrict__ dt1, float* __restrict__ dl1) {
  __shared__ float sXT[64][128];  // [k][token] transposed
  __shared__ float sW[24][64];    // [col][k]
  int tid = threadIdx.x;
  int tok2 = tid & 63, cg = tid >> 6;   // cg owns cols [cg*6, cg*6+6)
  int dir = blockIdx.y;
  int tok_base = blockIdx.x * 128;

  // staging: 2 threads per token, 32 consecutive k-floats each (8x v4f)
  int st_tok = tid >> 1, st_k0 = (tid & 1) * 32;
  const float* xg = x + (size_t)(tok_base + st_tok) * DMODEL + st_k0;
  unsigned short* xbo =
      (unsigned short*)xbf + (size_t)(tok_base + st_tok) * DMODEL + st_k0;
  const float* wb = dir ? in_w1 : in_w0;
  const float* wrow = wb + (size_t)NROWS_XBC * DMODEL;

  float acc0[6], acc1[6];
#pragma unroll
  for (int c = 0; c < 6; c++) { acc0[c] = 0.f; acc1[c] = 0.f; }

#pragma unroll 1
  for (int kc = 0; kc < 12; kc++) {   // 768 / 64
#pragma unroll
    for (int i = 0; i < 8; i++) {
      v4f v = *(const v4f*)(xg + kc * 64 + i * 4);
#pragma unroll
      for (int j = 0; j < 4; j++) sXT[st_k0 + i * 4 + j][st_tok] = v[j];
      if (dir == 0) {   // emit x_bf (identical values to old cast_x_kernel)
        v2u32 o;
        o[0] = (unsigned int)f2us(v[0]) | ((unsigned int)f2us(v[1]) << 16);
        o[1] = (unsigned int)f2us(v[2]) | ((unsigned int)f2us(v[3]) << 16);
        *(v2u32*)(xbo + kc * 64 + i * 4) = o;
      }
    }
    for (int i = tid; i < 24 * 16; i += 256) {
      int col = i >> 4, k4 = i & 15;
      *(v4f*)&sW[col][k4 * 4] =
          *(const v4f*)(wrow + (size_t)col * DMODEL + kc * 64 + k4 * 4);
    }
    __syncthreads();
#pragma unroll 2
    for (int k4 = 0; k4 < 16; k4++) {
      float xa[4], xb[4];
#pragma unroll
      for (int j = 0; j < 4; j++) {
        xa[j] = sXT[k4 * 4 + j][tok2];
        xb[j] = sXT[k4 * 4 + j][tok2 + 64];
      }
#pragma unroll
      for (int c = 0; c < 6; c++) {
        v4f wv = *(const v4f*)&sW[cg * 6 + c][k4 * 4];
#pragma unroll
        for (int j = 0; j < 4; j++) {
          acc0[c] = fmaf(xa[j], wv[j], acc0[c]);
          acc1[c] = fmaf(xb[j], wv[j], acc1[c]);
        }
      }
    }
    __syncthreads();
  }

  // epilogue: exact fp32 softplus / decay (identical formulas; h-major store)
  const float* dtB = dir ? dt_bias1 : dt_bias0;
  const float* Alg = dir ? A_log1 : A_log0;
  float* dto = dir ? dt1 : dt0;
  float* dlo = dir ? dl1 : dl0;
#pragma unroll
  for (int t = 0; t < 2; t++) {
    int r = tok_base + t * 64 + tok2;
    size_t row = dir ? (size_t)flip_row(r) : (size_t)r;
#pragma unroll
    for (int c = 0; c < 6; c++) {
      int h = cg * 6 + c;
      float v = (t ? acc1[c] : acc0[c]) + dtB[h];
      float dtv = (v > 20.f) ? v : log1pf(expf(v));
      dto[(size_t)h * NTOK + row] = dtv;
      dlo[(size_t)h * NTOK + row] = -dtv * expf(Alg[h]);
    }
  }
}

// ---------------- conv+silu for B/C channels -> per-chunk blobs ----------------
// Thread = (token, 8-channel octet): 4x v8u taps, 8 outputs, one 16B store.
__global__ void conv_bc_kernel(const bf16* __restrict__ xbcr,
                               const float* __restrict__ conv_w,
                               const float* __restrict__ conv_b,
                               bf16* __restrict__ Bblob, bf16* __restrict__ Cblob) {
  int idx = blockIdx.x * 256 + threadIdx.x;  // NTOK*16
  int token = idx >> 4, oct = idx & 15;
  int b = token >> 12, l = token & 4095, c = l >> 6, s = l & 63;
  int ch0 = 1536 + oct * 8;
  const unsigned short* xp = (const unsigned short*)xbcr;
  v8u tv[4];
#pragma unroll
  for (int j = 0; j < 4; j++) {
    int ls = l - 3 + j;
    v8u z = {0, 0, 0, 0, 0, 0, 0, 0};
    tv[j] = z;
    if (ls >= 0)
      tv[j] = *(const v8u*)(xp + (size_t)((b << 12) | ls) * CONVDIM + ch0);
  }
  v8u ov;
#pragma unroll
  for (int e = 0; e < 8; e++) {
    int ch = ch0 + e;
    const float* w4 = conv_w + ch * 4;
    float acc = conv_b[ch];
#pragma unroll
    for (int j = 0; j < 4; j++) acc += us2f(tv[j][e]) * w4[j];
    ov[e] = f2us(acc / (1.f + __expf(-acc)));
  }
  size_t base = ((size_t)((b * 64 + c) * 64 + s)) * 64;
  int ch7 = oct * 8;
  if (ch7 < 64) *(v8u*)((unsigned short*)Bblob + base + ch7) = ov;
  else          *(v8u*)((unsigned short*)Cblob + base + ch7 - 64) = ov;
}

// ---------------- chunked SSD: intra-chunk kernel (MFMA) ----------------
__global__ __launch_bounds__(256) void chunk_intra_kernel(
    const bf16* __restrict__ xbcr, const bf16* __restrict__ Bblob,
    const bf16* __restrict__ Cblob, const float* __restrict__ conv_w,
    const float* __restrict__ conv_b, const float* __restrict__ dtb,
    const float* __restrict__ dlb, const float* __restrict__ Dp,
    bf16* __restrict__ Yblob, bf16* __restrict__ Gblob, float* __restrict__ laq) {
  int blk = blockIdx.x;
  int c = blk & 63, bh = blk >> 6;
  int h = bh % HN, b = bh / HN;
  int tid = threadIdx.x, lane = tid & 63, wv = tid >> 6;
  int l15 = lane & 15, quad = lane >> 4;
  int tok0 = b * SEQL + c * 64;

  __shared__ unsigned short sXT[64][LS];  // [p][s]
  __shared__ unsigned short sB [64][LS];  // [s][n]; later sY [t][p]
  __shared__ unsigned short sBT[64][LS];  // [n][s] dG-scaled
  __shared__ unsigned short sC [64][LS];  // [t][n]; later sG [p][n]
  // rawX stride 72 shorts (144B): v8u rows 16B-aligned; dead before W written
  __shared__ union { unsigned short rawX[67][72]; unsigned short W[64][LS]; } sU;
  __shared__ float sla[64], sdt[64], sdG[64];

  // rawX staging: 67 rows x 8 v8u = 536 16B units (coalesced: 8 thr/row)
  for (int i = tid; i < 536; i += 256) {
    int r = i >> 3, j = i & 7;
    int l = c * 64 + r - 3;
    v8u v = {0, 0, 0, 0, 0, 0, 0, 0};
    if (l >= 0)
      v = *(const v8u*)((const unsigned short*)xbcr +
                        (size_t)(b * SEQL + l) * CONVDIM + h * 64 + j * 8);
    *(v8u*)&sU.rawX[r][j * 8] = v;
  }
  {
    const v8u* gB = (const v8u*)((const unsigned short*)Bblob + ((size_t)(b * 64 + c)) * 4096);
    const v8u* gC = (const v8u*)((const unsigned short*)Cblob + ((size_t)(b * 64 + c)) * 4096);
    int r0 = tid >> 3, g0 = tid & 7;
#pragma unroll
    for (int it = 0; it < 2; it++) {
      int row = r0 + it * 32;
      *(v8u*)&sB[row][g0 * 8] = gB[row * 8 + g0];
      *(v8u*)&sC[row][g0 * 8] = gC[row * 8 + g0];
    }
  }
  if (wv == 0) {  // log-decay prefix scan (h-major inputs: coalesced)
    float dtv = dtb[(size_t)h * NTOK + tok0 + lane];
    float lg = dlb[(size_t)h * NTOK + tok0 + lane];
#pragma unroll
    for (int d = 1; d < 64; d <<= 1) {
      float o = __shfl_up(lg, d);
      if (lane >= d) lg += o;
    }
    sla[lane] = lg;
    sdt[lane] = dtv;
    float la63 = __shfl(lg, 63);
    sdG[lane] = __expf(la63 - lg) * dtv;
    if (lane == 63) laq[blk] = __expf(la63);
  }
  __syncthreads();

  float Dh = Dp[h];
  {
    int s = lane;
    // conv+silu: wave wv owns p in [wv*16, wv*16+16) as 2 octets; 4x v8u reads
#pragma unroll
    for (int o = 0; o < 2; o++) {
      int p0 = (wv * 2 + o) * 8;
      v8u r0 = *(const v8u*)&sU.rawX[s + 0][p0];
      v8u r1 = *(const v8u*)&sU.rawX[s + 1][p0];
      v8u r2 = *(const v8u*)&sU.rawX[s + 2][p0];
      v8u r3 = *(const v8u*)&sU.rawX[s + 3][p0];
#pragma unroll
      for (int pp = 0; pp < 8; pp++) {
        int ch = h * 64 + p0 + pp;
        const float* w4 = conv_w + ch * 4;
        float acc = conv_b[ch] + us2f(r0[pp]) * w4[0] + us2f(r1[pp]) * w4[1] +
                    us2f(r2[pp]) * w4[2] + us2f(r3[pp]) * w4[3];
        sXT[p0 + pp][s] = f2us(acc / (1.f + __expf(-acc)));
      }
    }
#pragma unroll
    for (int it = 0; it < 16; it++) {
      int n = wv + it * 4;
      sBT[n][s] = f2us(us2f(sB[s][n]) * sdG[s]);
    }
  }
  __syncthreads();

  {  // W = C @ B^T, masked decay
    v4f acc[4];
#pragma unroll
    for (int j = 0; j < 4; j++) acc[j] = {0.f, 0.f, 0.f, 0.f};
    __builtin_amdgcn_s_setprio(1);
#pragma unroll
    for (int k0 = 0; k0 < 2; k0++) {
      v8s a = *(const v8s*)&sC[16 * wv + l15][k0 * 32 + quad * 8];
#pragma unroll
      for (int j = 0; j < 4; j++) {
        v8s bb = *(const v8s*)&sB[16 * j + l15][k0 * 32 + quad * 8];
        acc[j] = __builtin_amdgcn_mfma_f32_16x16x32_bf16(a, bb, acc[j], 0, 0, 0);
      }
    }
    __builtin_amdgcn_s_setprio(0);
    float lat[4];
#pragma unroll
    for (int r = 0; r < 4; r++) lat[r] = sla[16 * wv + quad * 4 + r];
#pragma unroll
    for (int j = 0; j < 4; j++) {
      int s = 16 * j + l15;
      float las = sla[s], dts = sdt[s];
#pragma unroll
      for (int r = 0; r < 4; r++) {
        int t = 16 * wv + quad * 4 + r;
        float w = (s <= t) ? __expf(lat[r] - las) * dts * acc[j][r] : 0.f;
        sU.W[t][s] = f2us(w);
      }
    }
  }
  __syncthreads();

  {  // y = W @ X + D*x; G = X @ BT
    v4f ya[4], ga[4];
#pragma unroll
    for (int j = 0; j < 4; j++) {
      ya[j] = {0.f, 0.f, 0.f, 0.f};
      ga[j] = {0.f, 0.f, 0.f, 0.f};
    }
    __builtin_amdgcn_s_setprio(1);
#pragma unroll
    for (int k0 = 0; k0 < 2; k0++) {
      v8s aw = *(const v8s*)&sU.W[16 * wv + l15][k0 * 32 + quad * 8];
      v8s ax = *(const v8s*)&sXT[16 * wv + l15][k0 * 32 + quad * 8];
#pragma unroll
      for (int j = 0; j < 4; j++) {
        v8s bx = *(const v8s*)&sXT[16 * j + l15][k0 * 32 + quad * 8];
        v8s bt = *(const v8s*)&sBT[16 * j + l15][k0 * 32 + quad * 8];
        ya[j] = __builtin_amdgcn_mfma_f32_16x16x32_bf16(aw, bx, ya[j], 0, 0, 0);
        ga[j] = __builtin_amdgcn_mfma_f32_16x16x32_bf16(ax, bt, ga[j], 0, 0, 0);
      }
    }
    __builtin_amdgcn_s_setprio(0);
#pragma unroll
    for (int j = 0; j < 4; j++) {
      int col = 16 * j + l15;
#pragma unroll
      for (int r = 0; r < 4; r++) {
        int row = 16 * wv + quad * 4 + r;
        float yv = ya[j][r] + Dh * us2f(sXT[col][row]);
        sB[row][col] = f2us(yv);
        sC[row][col] = f2us(ga[j][r]);
      }
    }
  }
  __syncthreads();

  {  // blob out: 2 passes of 16B
    v8u* gY = (v8u*)(Yblob + (size_t)blk * 4096);
    v8u* gG = (v8u*)(Gblob + (size_t)blk * 4096);
#pragma unroll
    for (int it = 0; it < 2; it++) {
      int i = tid + it * 256;
      int row = i >> 3, j = i & 7;
      gY[row * 8 + j] = *(const v8u*)&sB[row][j * 8];
      gG[row * 8 + j] = *(const v8u*)&sC[row][j * 8];
    }
  }
}

// ---------------- chunked SSD: inter-chunk state recurrence ----------------
// 4 blocks per (b,h) so all 256 CUs participate (384 blocks total).
__global__ __launch_bounds__(256) void state_scan_kernel(
    bf16* __restrict__ blob, const float* __restrict__ laq) {
  int blk = blockIdx.x;
  int bh = blk >> 2, qq = blk & 3;
  int tid = threadIdx.x;
  size_t base = (size_t)bh * 64 * 4096 +
                (size_t)(qq * 16 + (tid >> 4)) * 64 + (size_t)(tid & 15) * 4;
  float S[4];
#pragma unroll
  for (int i = 0; i < 4; i++) S[i] = 0.f;
  for (int c = 0; c < 64; c++) {
    float q = laq[bh * 64 + c];
    unsigned short* gp = (unsigned short*)blob + base + (size_t)c * 4096;
    v4u ga = *(v4u*)gp;
    v4u pa;
#pragma unroll
    for (int i = 0; i < 4; i++) pa[i] = f2us(S[i]);
    *(v4u*)gp = pa;
#pragma unroll
    for (int i = 0; i < 4; i++) S[i] = q * S[i] + us2f(ga[i]);
  }
}

// ---------------- chunked SSD: inter-chunk y contribution (MFMA) ----------------
// Prefix state staged into LDS (sS) during the coalesced staging phase.
__global__ __launch_bounds__(256) void chunk_inter_kernel(
    const bf16* __restrict__ Cblob, const float* __restrict__ dlb,
    const bf16* __restrict__ blob, bf16* __restrict__ Yblob) {
  int blk = blockIdx.x;
  int c = blk & 63, bh = blk >> 6;
  int h = bh % HN, b = bh / HN;
  int tid = threadIdx.x, lane = tid & 63, wv = tid >> 6;
  int l15 = lane & 15, quad = lane >> 4;
  int tok0 = b * SEQL + c * 64;

  __shared__ unsigned short sC[64][LS];
  __shared__ unsigned short sS[64][LS];
  __shared__ unsigned short sY[64][LS];
  __shared__ float sel[64];

  {
    const v8u* gC = (const v8u*)((const unsigned short*)Cblob + ((size_t)(b * 64 + c)) * 4096);
    const v8u* gS = (const v8u*)((const unsigned short*)blob + (size_t)blk * 4096);
    int r0 = tid >> 3, g0 = tid & 7;
#pragma unroll
    for (int it = 0; it < 2; it++) {
      int row = r0 + it * 32;
      *(v8u*)&sC[row][g0 * 8] = gC[row * 8 + g0];
      *(v8u*)&sS[row][g0 * 8] = gS[row * 8 + g0];
    }
  }
  if (wv == 0) {  // h-major dlb: coalesced
    float lg = dlb[(size_t)h * NTOK + tok0 + lane];
#pragma unroll
    for (int d = 1; d < 64; d <<= 1) {
      float o = __shfl_up(lg, d);
      if (lane >= d) lg += o;
    }
    sel[lane] = __expf(lg);
  }
  __syncthreads();
  {
    v4f acc[4];
#pragma unroll
    for (int j = 0; j < 4; j++) acc[j] = {0.f, 0.f, 0.f, 0.f};
    __builtin_amdgcn_s_setprio(1);
#pragma unroll
    for (int k0 = 0; k0 < 2; k0++) {
      v8s a = *(const v8s*)&sC[16 * wv + l15][k0 * 32 + quad * 8];
#pragma unroll
      for (int j = 0; j < 4; j++) {
        v8s bS = *(const v8s*)&sS[16 * j + l15][k0 * 32 + quad * 8];
        acc[j] = __builtin_amdgcn_mfma_f32_16x16x32_bf16(a, bS, acc[j], 0, 0, 0);
      }
    }
    __builtin_amdgcn_s_setprio(0);
    float selt[4];
#pragma unroll
    for (int r = 0; r < 4; r++) selt[r] = sel[16 * wv + quad * 4 + r];
#pragma unroll
    for (int j = 0; j < 4; j++)
#pragma unroll
      for (int r = 0; r < 4; r++)
        sY[16 * wv + quad * 4 + r][16 * j + l15] = f2us(selt[r] * acc[j][r]);
  }
  __syncthreads();
  {  // Y RMW: 2 passes of 16B
    v8u* gY = (v8u*)(Yblob + (size_t)blk * 4096);
#pragma unroll
    for (int it = 0; it < 2; it++) {
      int i = tid + it * 256;
      int row = i >> 3, j = i & 7;
      v8u old = gY[row * 8 + j];
      v8u add = *(const v8u*)&sY[row][j * 8];
      v8u outv;
#pragma unroll
      for (int e = 0; e < 8; e++) outv[e] = f2us(us2f(old[e]) + us2f(add[e]));
      gY[row * 8 + j] = outv;
    }
  }
}

// ---------------- gated RMSNorm: blob y + z rows -> ynorm rows ----------------
// Paired (4B) loads/stores: 3 iterations of 2 channels.
// out_ldc: output row stride (elements); out_flip: write row = flip(token).
__global__ __launch_bounds__(256) void norm_kernel(
    const bf16* __restrict__ Yblob, const bf16* __restrict__ z,
    const float* __restrict__ norm_w, bf16* __restrict__ out,
    int out_ldc, int out_flip) {
  int token = blockIdx.x;
  int tid = threadIdx.x;
  int b = token >> 12, l = token & 4095, c = l >> 6, t = l & 63;
  const unsigned short* zp = (const unsigned short*)z + (size_t)token * DINNER;
  float vals[6];
  float ss = 0.f;
#pragma unroll
  for (int i = 0; i < 3; i++) {
    int q = tid + i * 256;          // pair index 0..767
    int ch = q * 2;
    int hh = ch >> 6, p = ch & 63;  // p even
    size_t yi = ((((size_t)(b * HN + hh)) * 64 + c) * 64 + t) * 64 + p;
    unsigned int yv2 = *(const unsigned int*)((const unsigned short*)Yblob + yi);
    unsigned int zv2 = *(const unsigned int*)(zp + ch);
#pragma unroll
    for (int e = 0; e < 2; e++) {
      float yv = us2f((unsigned short)((yv2 >> (16 * e)) & 0xffff));
      float zv = us2f((unsigned short)((zv2 >> (16 * e)) & 0xffff));
      float g = zv / (1.f + __expf(-zv));
      float v = yv * g;
      vals[i * 2 + e] = v;
      ss += v * v;
    }
  }
  for (int off = 32; off > 0; off >>= 1) ss += __shfl_down(ss, off);
  __shared__ float sred[4];
  if ((tid & 63) == 0) sred[tid >> 6] = ss;
  __syncthreads();
  float tot = sred[0] + sred[1] + sred[2] + sred[3];
  float scale = rsqrtf(tot / (float)DINNER + 1e-5f);
  size_t orow = out_flip ? (size_t)flip_row(token) : (size_t)token;
#pragma unroll
  for (int i = 0; i < 3; i++) {
    int q = tid + i * 256;
    int ch = q * 2;
    unsigned int o =
        (unsigned int)f2us(vals[i * 2] * scale * norm_w[ch]) |
        ((unsigned int)f2us(vals[i * 2 + 1] * scale * norm_w[ch + 1]) << 16);
    *(unsigned int*)((unsigned short*)out + orow * out_ldc + ch) = o;
  }
}

// ---------------- launch ----------------
extern "C" void kernel_launch(void* const* d_in, const int* in_sizes, int n_in,
                              void* d_out, int out_size, void* d_ws, size_t ws_size,
                              hipStream_t stream) {
  const float* x = (const float*)d_in[0];
  const float* fus_w = (const float*)d_in[1];
  const float* fus_b = (const float*)d_in[2];
  const float* in_w[2] = {(const float*)d_in[3], (const float*)d_in[11]};
  const float* conv_w[2] = {(const float*)d_in[4], (const float*)d_in[12]};
  const float* conv_b[2] = {(const float*)d_in[5], (const float*)d_in[13]};
  const float* dt_bias[2] = {(const float*)d_in[6], (const float*)d_in[14]};
  const float* A_log[2] = {(const float*)d_in[7], (const float*)d_in[15]};
  const float* Dp[2] = {(const float*)d_in[8], (const float*)d_in[16]};
  const float* norm_w[2] = {(const float*)d_in[9], (const float*)d_in[17]};
  const float* out_w[2] = {(const float*)d_in[10], (const float*)d_in[18]};
  (void)in_sizes; (void)n_in;

  char* ws = (char*)d_ws;
  size_t off = 0;
  auto alloc = [&](size_t bytes) {
    size_t o = off;
    off = (off + bytes + 255) & ~(size_t)255;
    return o;
  };
  bf16* x_bf  = (bf16*)(ws + alloc((size_t)NTOK * DMODEL * 2));              // 25.2 MB
  bf16* w_in  = (bf16*)(ws + alloc((size_t)NROWS_XBC * DMODEL * 2));         //  4.9 MB
  bf16* wf1   = (bf16*)(ws + alloc((size_t)2 * DMODEL * DMODEL * 2));        //  2.4 MB (x2 dirs)
  bf16* owT   = (bf16*)(ws + alloc((size_t)2 * DINNER * DMODEL * 2));        //  4.7 MB (x2 dirs)
  bf16* wc    = (bf16*)(ws + alloc((size_t)2 * DMODEL * DINNER * 2));        //  4.7 MB (x2 dirs / interleaved)
  bf16* xbcr  = (bf16*)(ws + alloc((size_t)NTOK * CONVDIM * 2));             // 54.5 MB (ynorm aliases)
  float* dtb0 = (float*)(ws + alloc((size_t)NTOK * HN * 4));                 //  1.6 MB
  float* dlb0 = (float*)(ws + alloc((size_t)NTOK * HN * 4));                 //  1.6 MB
  float* dtb1 = (float*)(ws + alloc((size_t)NTOK * HN * 4));                 //  1.6 MB
  float* dlb1 = (float*)(ws + alloc((size_t)NTOK * HN * 4));                 //  1.6 MB
  float* laq  = (float*)(ws + alloc((size_t)BATCHN * HN * NCHUNK * 4));      //  0.02 MB
  bf16* Bblob = (bf16*)(ws + alloc((size_t)NTOK * DSTATE * 2));              //  2.1 MB
  bf16* Cblob = (bf16*)(ws + alloc((size_t)NTOK * DSTATE * 2));              //  2.1 MB
  bf16* Gblob = (bf16*)(ws + alloc((size_t)NTOK * DINNER * 2));              // 50.3 MB (z aliases)
  bf16* Yblob = (bf16*)(ws + alloc((size_t)NTOK * DINNER * 2));              // 50.3 MB
  size_t off_base = off;
  bf16* ynormC = (bf16*)(ws + alloc((size_t)NTOK * 2 * DINNER * 2));         // 100.7 MB (combined path)
  int combined = ws_size >= off;  // runtime path choice; fallback = round-10

  bf16* zbuf  = Gblob;  // z GEMM output reuses G/prefix blob (dead after chunk_inter)
  bf16* ynorm = xbcr;   // fallback: normalized y reuses xbcr (dead after chunk_inter)
  float* dtbs[2] = {dtb0, dtb1};
  float* dlbs[2] = {dlb0, dlb1};

  if (ws_size < off_base) {  // diagnostic: clean absmax(=max|ref|) failure, not a crash
    hipMemsetAsync(d_out, 0, (size_t)out_size * 4, stream);
    return;
  }

  // exact fp32 dt + log-decay, both directions in one x pass; also emits x_bf
  dt_fused_kernel<<<dim3(NTOK / 128, 2), 256, 0, stream>>>(
      x, x_bf, in_w[0], in_w[1], dt_bias[0], dt_bias[1], A_log[0], A_log[1],
      dtb0, dlb0, dtb1, dlb1);

  // combined weights wc_d = fus_half_d @ out_w_d (768x1536), both dirs batched.
  // combined path: interleaved layout wcC[768][3072] via ldc=3072 + col-offset.
  for (int d = 0; d < 2; d++) {
    cast_strided_kernel<<<(DMODEL * DMODEL) / 1024, 256, 0, stream>>>(
        fus_w + d * DMODEL, wf1 + (size_t)d * DMODEL * DMODEL, DMODEL, 2 * DMODEL);
    transpose_ow_kernel<<<(DINNER * DMODEL) / 1024, 256, 0, stream>>>(
        out_w[d], owT + (size_t)d * DINNER * DMODEL);
  }
  if (combined) {
    gemm_lds<true><<<dim3(DMODEL / 128, DINNER / 128, 2), 256, 0, stream>>>(
        wf1, owT, wc, DMODEL, 2 * DINNER, 0, 0, 0,
        (size_t)DMODEL * DMODEL, (size_t)DINNER * DMODEL, (size_t)DINNER, nullptr);
  } else {
    gemm_lds<true><<<dim3(DMODEL / 128, DINNER / 128, 2), 256, 0, stream>>>(
        wf1, owT, wc, DMODEL, DINNER, 0, 0, 0,
        (size_t)DMODEL * DMODEL, (size_t)DINNER * DMODEL, (size_t)DMODEL * DINNER,
        nullptr);
  }

  for (int dir = 0; dir < 2; dir++) {
    cast_kernel<<<(NROWS_XBC * DMODEL) / 1024, 256, 0, stream>>>(in_w[dir], w_in);
    // in-proj xBC part (in_w rows 1536..3200) -> xbcr
    gemm_lds<true><<<dim3(NTOK / 128, CONVDIM / 128), 256, 0, stream>>>(
        x_bf, w_in + (size_t)DINNER * DMODEL, xbcr, DMODEL, CONVDIM, dir, 0, 0,
        0, 0, 0, nullptr);
    // B/C conv+silu once -> per-chunk blobs
    conv_bc_kernel<<<(NTOK * 16) / 256, 256, 0, stream>>>(
        xbcr, conv_w[dir], conv_b[dir], Bblob, Cblob);
    // chunked SSD
    chunk_intra_kernel<<<BATCHN * HN * NCHUNK, 256, 0, stream>>>(
        xbcr, Bblob, Cblob, conv_w[dir], conv_b[dir], dtbs[dir], dlbs[dir], Dp[dir],
        Yblob, Gblob, laq);
    state_scan_kernel<<<BATCHN * HN * 4, 256, 0, stream>>>(Gblob, laq);
    chunk_inter_kernel<<<BATCHN * HN * NCHUNK, 256, 0, stream>>>(Cblob, dlbs[dir], Gblob, Yblob);
    // in-proj z part (in_w rows 0..1536) -> zbuf (blob region, now dead)
    gemm_lds<true><<<dim3(NTOK / 128, DINNER / 128), 256, 0, stream>>>(
        x_bf, w_in, zbuf, DMODEL, DINNER, dir, 0, 0, 0, 0, 0, nullptr);
    if (combined) {
      // gated RMSNorm -> ynormC half; dir1 rows pre-unflipped (= old flip_c)
      norm_kernel<<<NTOK, 256, 0, stream>>>(
          Yblob, zbuf, norm_w[dir], ynormC + (size_t)dir * DINNER, 2 * DINNER, dir);
    } else {
      // gated RMSNorm -> ynorm rows (xbcr region, now dead)
      norm_kernel<<<NTOK, 256, 0, stream>>>(
          Yblob, zbuf, norm_w[dir], ynorm, DINNER, 0);
      // out-proj + fusion: d_out (+)= ynorm @ wc_dir^T (dir1 un-flips, accumulates)
      gemm_lds<false><<<dim3(NTOK / 128, DMODEL / 128), 256, 0, stream>>>(
          ynorm, wc + (size_t)dir * DMODEL * DINNER, d_out, DINNER, DMODEL, 0, dir, dir,
          0, 0, 0, dir == 0 ? fus_b : nullptr);
    }
  }

  if (combined) {
    // single K=3072 out-proj+fusion: d_out = ynormC @ wcC^T + fus_b (no RMW)
    gemm_lds<false><<<dim3(NTOK / 128, DMODEL / 128), 256, 0, stream>>>(
        ynormC, wc, d_out, 2 * DINNER, DMODEL, 0, 0, 0, 0, 0, 0, fus_b);
  }
}